// Round 4
// baseline (781.530 us; speedup 1.0000x reference)
//
#include <hip/hip_runtime.h>
#include <math.h>

#define NNODE 50000
#define NEDGE 800000
#define NFEAT 256
#define NHID  128
#define NTEST 5000
#define NTRAIN 5000
#define NCLS  16
#define TOPK  20
#define CB    1024          // cols per score block
#define NJT   5             // col tiles (5120 padded)
#define RB    16            // rows per score block
#define NTPAD (NJT * CB)    // 5120

typedef __attribute__((ext_vector_type(8))) short short8v;
typedef __attribute__((ext_vector_type(4))) float f32x4;

// ---------------- GEMM: C[M x 128] = op(A)[M x KT] @ B[KT x 128] ----------------
template<int KT, bool RELU>
__global__ __launch_bounds__(256)
void gemm128(const float* __restrict__ A, const float* __restrict__ B,
             float* __restrict__ C, int M) {
  __shared__ float As[32][68];   // [k][m], +4 pad
  __shared__ float Bs[32][128];  // [k][n]
  const int tid = threadIdx.x;
  const int ty = tid >> 4, tx = tid & 15;
  const int m0 = blockIdx.x * 64;
  float acc[4][8];
#pragma unroll
  for (int i = 0; i < 4; ++i)
#pragma unroll
    for (int j = 0; j < 8; ++j) acc[i][j] = 0.f;

  for (int k0 = 0; k0 < KT; k0 += 32) {
#pragma unroll
    for (int p = 0; p < 2; ++p) {
      int li = p * 256 + tid;
      int r  = li >> 3;
      int kc = (li & 7) << 2;
      int gr = m0 + r; if (gr > M - 1) gr = M - 1;
      float4 v = *reinterpret_cast<const float4*>(&A[(size_t)gr * KT + k0 + kc]);
      if (RELU) { v.x=fmaxf(v.x,0.f); v.y=fmaxf(v.y,0.f); v.z=fmaxf(v.z,0.f); v.w=fmaxf(v.w,0.f); }
      As[kc+0][r]=v.x; As[kc+1][r]=v.y; As[kc+2][r]=v.z; As[kc+3][r]=v.w;
    }
#pragma unroll
    for (int p = 0; p < 4; ++p) {
      int li = p * 256 + tid;
      int r  = li >> 5;
      int c4 = (li & 31) << 2;
      *reinterpret_cast<float4*>(&Bs[r][c4]) =
        *reinterpret_cast<const float4*>(&B[(size_t)(k0 + r) * 128 + c4]);
    }
    __syncthreads();
#pragma unroll
    for (int k = 0; k < 32; ++k) {
      float4 a  = *reinterpret_cast<const float4*>(&As[k][ty << 2]);
      float4 b0 = *reinterpret_cast<const float4*>(&Bs[k][tx << 2]);
      float4 b1 = *reinterpret_cast<const float4*>(&Bs[k][64 + (tx << 2)]);
      float av[4] = {a.x, a.y, a.z, a.w};
#pragma unroll
      for (int i = 0; i < 4; ++i) {
        acc[i][0] += av[i]*b0.x; acc[i][1] += av[i]*b0.y;
        acc[i][2] += av[i]*b0.z; acc[i][3] += av[i]*b0.w;
        acc[i][4] += av[i]*b1.x; acc[i][5] += av[i]*b1.y;
        acc[i][6] += av[i]*b1.z; acc[i][7] += av[i]*b1.w;
      }
    }
    __syncthreads();
  }
#pragma unroll
  for (int i = 0; i < 4; ++i) {
    int row = m0 + (ty << 2) + i;
    if (row < M) {
      float4 o0 = {acc[i][0], acc[i][1], acc[i][2], acc[i][3]};
      float4 o1 = {acc[i][4], acc[i][5], acc[i][6], acc[i][7]};
      *reinterpret_cast<float4*>(&C[(size_t)row * 128 + (tx << 2)]) = o0;
      *reinterpret_cast<float4*>(&C[(size_t)row * 128 + 64 + (tx << 2)]) = o1;
    }
  }
}

// ---------------- CSR build ----------------
__global__ __launch_bounds__(256)
void zero_cnt(int* __restrict__ cnt) {
  int i = blockIdx.x * 256 + threadIdx.x;
  if (i < NNODE) cnt[i] = 0;
}

__global__ __launch_bounds__(256)
void hist_dst(const int* __restrict__ edst, int* __restrict__ cnt) {
  int e = blockIdx.x * 256 + threadIdx.x;
  if (e < NEDGE) atomicAdd(&cnt[edst[e]], 1);
}

#define SCHUNK 196
__global__ __launch_bounds__(256)
void scan_cnt(int* __restrict__ cnt) {
  __shared__ int part[256];
  const int t = threadIdx.x;
  const int base = t * SCHUNK;
  int s = 0;
  for (int i = 0; i < SCHUNK; ++i) {
    int idx = base + i;
    if (idx < NNODE) s += cnt[idx];
  }
  part[t] = s;
  __syncthreads();
  for (int off = 1; off < 256; off <<= 1) {
    int v = (t >= off) ? part[t - off] : 0;
    __syncthreads();
    part[t] += v;
    __syncthreads();
  }
  int run = part[t] - s;
  for (int i = 0; i < SCHUNK; ++i) {
    int idx = base + i;
    if (idx < NNODE) { int c = cnt[idx]; cnt[idx] = run; run += c; }
  }
}

__global__ __launch_bounds__(256)
void fill_csr(const int* __restrict__ esrc, const int* __restrict__ edst,
              const float* __restrict__ ew, int* __restrict__ cursor,
              int2* __restrict__ packed) {
  int e = blockIdx.x * 256 + threadIdx.x;
  if (e < NEDGE) {
    int d = edst[e];
    int p = atomicAdd(&cursor[d], 1);
    packed[p] = make_int2(esrc[e], __float_as_int(ew[e]));
  }
}

// ---------------- propagate as gather ----------------
__global__ __launch_bounds__(256)
void gather_nodes(const float* __restrict__ X, float* __restrict__ out,
                  const int* __restrict__ endoff, const int2* __restrict__ packed,
                  const float* __restrict__ bias) {
  int node = blockIdx.x * 2 + (threadIdx.x >> 7);
  int c = threadIdx.x & 127;
  int beg = node ? endoff[node - 1] : 0;
  int end = endoff[node];
  float acc = bias[c], acc2 = 0.f;
  int e = beg;
  for (; e + 1 < end; e += 2) {
    int2 p0 = packed[e], p1 = packed[e + 1];
    acc  += __int_as_float(p0.y) * X[(size_t)p0.x * 128 + c];
    acc2 += __int_as_float(p1.y) * X[(size_t)p1.x * 128 + c];
  }
  if (e < end) {
    int2 p = packed[e];
    acc += __int_as_float(p.y) * X[(size_t)p.x * 128 + c];
  }
  out[(size_t)node * 128 + c] = acc + acc2;
}

// ---------------- bf16 split helpers ----------------
__device__ inline void splitbf(float x, unsigned short& h, unsigned short& l) {
  unsigned u = __float_as_uint(x);
  unsigned hb = (u + 0x7fffu + ((u >> 16) & 1u)) >> 16;    // RNE to bf16
  float hf = __uint_as_float(hb << 16);
  float r = x - hf;
  unsigned ur = __float_as_uint(r);
  unsigned lb = (ur + 0x7fffu + ((ur >> 16) & 1u)) >> 16;
  h = (unsigned short)hb; l = (unsigned short)lb;
}

// gather + bf16-split: train emb -> Thi/Tlo [NTPAD][128] (zero pad),
// test emb -> Qhi/Qlo [5000][128], onehot gather -> lab [5000][16]
__global__ __launch_bounds__(256)
void gather_splits(const float* __restrict__ emb, const float* __restrict__ onehot,
                   const int* __restrict__ itr, const int* __restrict__ ite,
                   unsigned short* __restrict__ Thi, unsigned short* __restrict__ Tlo,
                   unsigned short* __restrict__ Qhi, unsigned short* __restrict__ Qlo,
                   float* __restrict__ lab) {
  int gid = blockIdx.x * 256 + threadIdx.x;
  if (gid < NTPAD * NHID) {
    int j = gid >> 7, c = gid & 127;
    unsigned short h = 0, l = 0;
    if (j < NTRAIN) splitbf(emb[(size_t)itr[j] * NHID + c], h, l);
    Thi[gid] = h; Tlo[gid] = l;
  } else if (gid < NTPAD * NHID + NTEST * NHID) {
    int i = gid - NTPAD * NHID;
    int j = i >> 7, c = i & 127;
    unsigned short h, l;
    splitbf(emb[(size_t)ite[j] * NHID + c], h, l);
    Qhi[i] = h; Qlo[i] = l;
  } else if (gid < NTPAD * NHID + NTEST * NHID + NTRAIN * NCLS) {
    int i = gid - NTPAD * NHID - NTEST * NHID;
    int j = i >> 4, c = i & 15;
    lab[i] = onehot[(size_t)itr[j] * NCLS + c];
  }
}

// ---------------- MFMA score tile + per-tile top-20 ----------------
// grid (313, 5). Block: 16 test rows x 1024 train cols, 4 waves.
// Wave w computes cols [256w, 256w+256): 16 col-tiles x 12 mfma (3-term split).
// Scores -> s[16][1024] LDS; wave w selects top-20 for rows 4w..4w+3.
__global__ __launch_bounds__(256)
void score_mfma(const unsigned short* __restrict__ Qhi, const unsigned short* __restrict__ Qlo,
                const unsigned short* __restrict__ Thi, const unsigned short* __restrict__ Tlo,
                float* __restrict__ cand_v, int* __restrict__ cand_i) {
  __shared__ float s[RB][CB];          // 64 KB
  const int tid = threadIdx.x;
  const int w = tid >> 6, lane = tid & 63;
  const int r0 = blockIdx.x * RB;
  const int j0 = blockIdx.y * CB;

  // A fragments (held for whole kernel): row = r0 + (lane&15), k = 32ks + (lane>>4)*8
  int arow = r0 + (lane & 15); if (arow > NTEST - 1) arow = NTEST - 1;
  const int koff = (lane >> 4) * 8;
  short8v ah[4], al[4];
#pragma unroll
  for (int ks = 0; ks < 4; ++ks) {
    ah[ks] = *reinterpret_cast<const short8v*>(&Qhi[(size_t)arow * 128 + ks * 32 + koff]);
    al[ks] = *reinterpret_cast<const short8v*>(&Qlo[(size_t)arow * 128 + ks * 32 + koff]);
  }

  const int srow = (lane >> 4) * 2;    // /2 rows handled below via reg mapping
#pragma unroll
  for (int t = 0; t < 16; ++t) {
    int col = j0 + w * 256 + t * 16 + (lane & 15);   // < NTPAD always
    const unsigned short* bh = &Thi[(size_t)col * 128 + koff];
    const unsigned short* bl = &Tlo[(size_t)col * 128 + koff];
    f32x4 a = {0.f, 0.f, 0.f, 0.f};
#pragma unroll
    for (int ks = 0; ks < 4; ++ks) {
      short8v bhv = *reinterpret_cast<const short8v*>(&bh[ks * 32]);
      short8v blv = *reinterpret_cast<const short8v*>(&bl[ks * 32]);
      a = __builtin_amdgcn_mfma_f32_16x16x32_bf16(ah[ks], bhv, a, 0, 0, 0);
      a = __builtin_amdgcn_mfma_f32_16x16x32_bf16(ah[ks], blv, a, 0, 0, 0);
      a = __builtin_amdgcn_mfma_f32_16x16x32_bf16(al[ks], bhv, a, 0, 0, 0);
    }
    // C layout: col = lane&15, row = (lane>>4)*4 + r
    int sc = w * 256 + t * 16 + (lane & 15);
    int sr = (lane >> 4) * 4;
#pragma unroll
    for (int r = 0; r < 4; ++r) s[sr + r][sc] = a[r];
  }
  (void)srow;
  __syncthreads();

  // per-wave selection: wave w owns rows 4w..4w+3
#pragma unroll
  for (int r = 0; r < 4; ++r) {
    const int m = w * 4 + r;
    float v[16];
#pragma unroll
    for (int k = 0; k < 16; ++k) {
      int jg = j0 + lane + 64 * k;
      v[k] = (jg < NTRAIN) ? s[m][lane + 64 * k] : -INFINITY;
    }
    float selv = 0.f; int seli = 0;
#pragma unroll
    for (int it = 0; it < TOPK; ++it) {
      float bv = v[0]; int bk = 0;
#pragma unroll
      for (int k = 1; k < 16; ++k)
        if (v[k] > bv) { bv = v[k]; bk = k; }
      int bj = lane + 64 * bk;
#pragma unroll
      for (int off = 1; off < 64; off <<= 1) {
        float ov = __shfl_xor(bv, off);
        int   oj = __shfl_xor(bj, off);
        if (ov > bv || (ov == bv && oj < bj)) { bv = ov; bj = oj; }
      }
      if (lane == it) { selv = bv; seli = j0 + bj; }
      int ck = bj >> 6;
      if ((bj & 63) == lane) {
#pragma unroll
        for (int k = 0; k < 16; ++k)
          if (k == ck) v[k] = -INFINITY;
      }
    }
    if (lane < TOPK && r0 + m < NTEST) {
      size_t o = ((size_t)(r0 + m) * NJT + blockIdx.y) * TOPK + lane;
      cand_v[o] = selv;
      cand_i[o] = seli;
    }
  }
}

// ---------------- merge candidates + softmax + preds ----------------
__global__ __launch_bounds__(256)
void merge_topk(const float* __restrict__ cand_v, const int* __restrict__ cand_i,
                const float* __restrict__ lab, float* __restrict__ out) {
  const int tid = threadIdx.x;
  const int wv = tid >> 6, lane = tid & 63;
  const int row = blockIdx.x * 4 + wv;
  const size_t base = (size_t)row * (NJT * TOPK);

  float c0 = -INFINITY, c1 = -INFINITY;
  int i0 = 0x7fffffff, i1 = 0x7fffffff;
  if (lane < NJT * TOPK)      { c0 = cand_v[base + lane];      i0 = cand_i[base + lane]; }
  if (lane + 64 < NJT * TOPK) { c1 = cand_v[base + lane + 64]; i1 = cand_i[base + lane + 64]; }

  float selv = 0.f; int seli = 0;
#pragma unroll
  for (int it = 0; it < TOPK; ++it) {
    float bv = c0; int bj = i0;
    if (c1 > bv || (c1 == bv && i1 < bj)) { bv = c1; bj = i1; }
#pragma unroll
    for (int off = 1; off < 64; off <<= 1) {
      float ov = __shfl_xor(bv, off);
      int   oj = __shfl_xor(bj, off);
      if (ov > bv || (ov == bv && oj < bj)) { bv = ov; bj = oj; }
    }
    if (lane == it) { selv = bv; seli = bj; }
    if (i0 == bj) c0 = -INFINITY;
    if (i1 == bj) c1 = -INFINITY;
  }
  float mx = __shfl(selv, 0);
  float wgt = (lane < TOPK) ? expf(selv - mx) : 0.f;
  float sum = wgt;
#pragma unroll
  for (int off = 1; off < 64; off <<= 1) sum += __shfl_xor(sum, off);

  float acc = 0.f;
#pragma unroll
  for (int i = 0; i < TOPK; ++i) {
    float wi = __shfl(wgt, i);
    int   ji = __shfl(seli, i);
    if (lane < NCLS) acc += wi * lab[(size_t)ji * NCLS + lane];
  }
  if (lane < NCLS) out[(size_t)row * NCLS + lane] = acc / sum;
}

extern "C" void kernel_launch(void* const* d_in, const int* in_sizes, int n_in,
                              void* d_out, int out_size, void* d_ws, size_t ws_size,
                              hipStream_t stream) {
  const float* feat   = (const float*)d_in[0];
  const float* ew     = (const float*)d_in[1];
  const float* onehot = (const float*)d_in[2];
  const float* W1     = (const float*)d_in[3];
  const float* b1     = (const float*)d_in[4];
  const float* W2     = (const float*)d_in[5];
  const float* b2     = (const float*)d_in[6];
  const int*   ei     = (const int*)d_in[7];
  const int*   itr    = (const int*)d_in[8];
  const int*   ite    = (const int*)d_in[9];
  float* out = (float*)d_out;
  float* ws  = (float*)d_ws;

  float* bufA   = ws;                                  // [NNODE][128]
  float* bufH   = bufA + (size_t)NNODE * NHID;         // [NNODE][128]
  int*   cursor = (int*)(bufH + (size_t)NNODE * NHID); // [NNODE]
  int2*  packed = (int2*)(cursor + ((NNODE + 15) & ~15)); // [NEDGE]
  // score-phase buffers alias the dead CSR packed region (6.4 MB > 5.5 MB used)
  unsigned short* Thi = (unsigned short*)packed;                 // [NTPAD][128]
  unsigned short* Tlo = Thi + (size_t)NTPAD * NHID;
  unsigned short* Qhi = Tlo + (size_t)NTPAD * NHID;              // [5000][128]
  unsigned short* Qlo = Qhi + (size_t)NTEST * NHID;
  float* lab = (float*)(Qlo + (size_t)NTEST * NHID);             // [5000][16]
  float* cand_v = bufA;                                // [5000][NJT][20] (bufA dead)
  int*   cand_i = (int*)(bufA + (size_t)NTEST * NJT * TOPK);

  const int* esrc = ei;
  const int* edst = ei + NEDGE;

  // CSR build
  zero_cnt<<<(NNODE + 255) / 256, 256, 0, stream>>>(cursor);
  hist_dst<<<(NEDGE + 255) / 256, 256, 0, stream>>>(edst, cursor);
  scan_cnt<<<1, 256, 0, stream>>>(cursor);
  fill_csr<<<(NEDGE + 255) / 256, 256, 0, stream>>>(esrc, edst, ew, cursor, packed);

  // layer 1 + layer 2
  gemm128<NFEAT, false><<<(NNODE + 63) / 64, 256, 0, stream>>>(feat, W1, bufA, NNODE);
  gather_nodes<<<NNODE / 2, 256, 0, stream>>>(bufA, bufH, cursor, packed, b1);
  gemm128<NHID, true><<<(NNODE + 63) / 64, 256, 0, stream>>>(bufH, W2, bufA, NNODE);
  gather_nodes<<<NNODE / 2, 256, 0, stream>>>(bufA, bufH, cursor, packed, b2);

  // scoring: gather + bf16 split, MFMA score tiles, merge
  int tot = NTPAD * NHID + NTEST * NHID + NTRAIN * NCLS;
  gather_splits<<<(tot + 255) / 256, 256, 0, stream>>>(
      bufH, onehot, itr, ite, Thi, Tlo, Qhi, Qlo, lab);
  score_mfma<<<dim3((NTEST + RB - 1) / RB, NJT), 256, 0, stream>>>(
      Qhi, Qlo, Thi, Tlo, cand_v, cand_i);
  merge_topk<<<NTEST / 4, 256, 0, stream>>>(cand_v, cand_i, lab, out);
}

// Round 5
// 687.404 us; speedup vs baseline: 1.1369x; 1.1369x over previous
//
#include <hip/hip_runtime.h>
#include <math.h>

#define NNODE 50000
#define NEDGE 800000
#define NFEAT 256
#define NHID  128
#define NTEST 5000
#define NTRAIN 5000
#define NCLS  16
#define TOPK  20
#define CB    1024          // cols per score block
#define NJT   5             // col tiles (5120 padded)
#define RB    16            // rows per score block
#define NTPAD (NJT * CB)    // 5120

typedef __attribute__((ext_vector_type(8))) short short8v;
typedef __attribute__((ext_vector_type(4))) float f32x4;

// swizzled score-LDS index: banks spread so both C-writes and selection reads
// are 2-way (free); fixes the 801K 4-way conflicts from round 4
#define SWZ(r, c) ((r) * CB + (((c) + 4 * (r)) & (CB - 1)))

// ---------------- GEMM: C[M x 128] = op(A)[M x KT] @ B[KT x 128] ----------------
template<int KT, bool RELU>
__global__ __launch_bounds__(256)
void gemm128(const float* __restrict__ A, const float* __restrict__ B,
             float* __restrict__ C, int M) {
  __shared__ float As[32][68];   // [k][m], +4 pad
  __shared__ float Bs[32][128];  // [k][n]
  const int tid = threadIdx.x;
  const int ty = tid >> 4, tx = tid & 15;
  const int m0 = blockIdx.x * 64;
  float acc[4][8];
#pragma unroll
  for (int i = 0; i < 4; ++i)
#pragma unroll
    for (int j = 0; j < 8; ++j) acc[i][j] = 0.f;

  for (int k0 = 0; k0 < KT; k0 += 32) {
#pragma unroll
    for (int p = 0; p < 2; ++p) {
      int li = p * 256 + tid;
      int r  = li >> 3;
      int kc = (li & 7) << 2;
      int gr = m0 + r; if (gr > M - 1) gr = M - 1;
      float4 v = *reinterpret_cast<const float4*>(&A[(size_t)gr * KT + k0 + kc]);
      if (RELU) { v.x=fmaxf(v.x,0.f); v.y=fmaxf(v.y,0.f); v.z=fmaxf(v.z,0.f); v.w=fmaxf(v.w,0.f); }
      As[kc+0][r]=v.x; As[kc+1][r]=v.y; As[kc+2][r]=v.z; As[kc+3][r]=v.w;
    }
#pragma unroll
    for (int p = 0; p < 4; ++p) {
      int li = p * 256 + tid;
      int r  = li >> 5;
      int c4 = (li & 31) << 2;
      *reinterpret_cast<float4*>(&Bs[r][c4]) =
        *reinterpret_cast<const float4*>(&B[(size_t)(k0 + r) * 128 + c4]);
    }
    __syncthreads();
#pragma unroll
    for (int k = 0; k < 32; ++k) {
      float4 a  = *reinterpret_cast<const float4*>(&As[k][ty << 2]);
      float4 b0 = *reinterpret_cast<const float4*>(&Bs[k][tx << 2]);
      float4 b1 = *reinterpret_cast<const float4*>(&Bs[k][64 + (tx << 2)]);
      float av[4] = {a.x, a.y, a.z, a.w};
#pragma unroll
      for (int i = 0; i < 4; ++i) {
        acc[i][0] += av[i]*b0.x; acc[i][1] += av[i]*b0.y;
        acc[i][2] += av[i]*b0.z; acc[i][3] += av[i]*b0.w;
        acc[i][4] += av[i]*b1.x; acc[i][5] += av[i]*b1.y;
        acc[i][6] += av[i]*b1.z; acc[i][7] += av[i]*b1.w;
      }
    }
    __syncthreads();
  }
#pragma unroll
  for (int i = 0; i < 4; ++i) {
    int row = m0 + (ty << 2) + i;
    if (row < M) {
      float4 o0 = {acc[i][0], acc[i][1], acc[i][2], acc[i][3]};
      float4 o1 = {acc[i][4], acc[i][5], acc[i][6], acc[i][7]};
      *reinterpret_cast<float4*>(&C[(size_t)row * 128 + (tx << 2)]) = o0;
      *reinterpret_cast<float4*>(&C[(size_t)row * 128 + 64 + (tx << 2)]) = o1;
    }
  }
}

// ---------------- CSR build ----------------
__global__ __launch_bounds__(256)
void zero_cnt(int* __restrict__ cnt) {
  int i = blockIdx.x * 256 + threadIdx.x;
  if (i < NNODE) cnt[i] = 0;
}

__global__ __launch_bounds__(256)
void hist_dst(const int* __restrict__ edst, int* __restrict__ cnt) {
  int e = blockIdx.x * 256 + threadIdx.x;
  if (e < NEDGE) atomicAdd(&cnt[edst[e]], 1);
}

#define SCHUNK 196
__global__ __launch_bounds__(256)
void scan_cnt(int* __restrict__ cnt) {
  __shared__ int part[256];
  const int t = threadIdx.x;
  const int base = t * SCHUNK;
  int s = 0;
  for (int i = 0; i < SCHUNK; ++i) {
    int idx = base + i;
    if (idx < NNODE) s += cnt[idx];
  }
  part[t] = s;
  __syncthreads();
  for (int off = 1; off < 256; off <<= 1) {
    int v = (t >= off) ? part[t - off] : 0;
    __syncthreads();
    part[t] += v;
    __syncthreads();
  }
  int run = part[t] - s;
  for (int i = 0; i < SCHUNK; ++i) {
    int idx = base + i;
    if (idx < NNODE) { int c = cnt[idx]; cnt[idx] = run; run += c; }
  }
}

__global__ __launch_bounds__(256)
void fill_csr(const int* __restrict__ esrc, const int* __restrict__ edst,
              const float* __restrict__ ew, int* __restrict__ cursor,
              int2* __restrict__ packed) {
  int e = blockIdx.x * 256 + threadIdx.x;
  if (e < NEDGE) {
    int d = edst[e];
    int p = atomicAdd(&cursor[d], 1);
    packed[p] = make_int2(esrc[e], __float_as_int(ew[e]));
  }
}

// ---------------- propagate as gather ----------------
__global__ __launch_bounds__(256)
void gather_nodes(const float* __restrict__ X, float* __restrict__ out,
                  const int* __restrict__ endoff, const int2* __restrict__ packed,
                  const float* __restrict__ bias) {
  int node = blockIdx.x * 2 + (threadIdx.x >> 7);
  int c = threadIdx.x & 127;
  int beg = node ? endoff[node - 1] : 0;
  int end = endoff[node];
  float acc = bias[c], acc2 = 0.f;
  int e = beg;
  for (; e + 1 < end; e += 2) {
    int2 p0 = packed[e], p1 = packed[e + 1];
    acc  += __int_as_float(p0.y) * X[(size_t)p0.x * 128 + c];
    acc2 += __int_as_float(p1.y) * X[(size_t)p1.x * 128 + c];
  }
  if (e < end) {
    int2 p = packed[e];
    acc += __int_as_float(p.y) * X[(size_t)p.x * 128 + c];
  }
  out[(size_t)node * 128 + c] = acc + acc2;
}

// ---------------- bf16 split helpers ----------------
__device__ inline void splitbf(float x, unsigned short& h, unsigned short& l) {
  unsigned u = __float_as_uint(x);
  unsigned hb = (u + 0x7fffu + ((u >> 16) & 1u)) >> 16;    // RNE to bf16
  float hf = __uint_as_float(hb << 16);
  float r = x - hf;
  unsigned ur = __float_as_uint(r);
  unsigned lb = (ur + 0x7fffu + ((ur >> 16) & 1u)) >> 16;
  h = (unsigned short)hb; l = (unsigned short)lb;
}

// gather + bf16-split
__global__ __launch_bounds__(256)
void gather_splits(const float* __restrict__ emb, const float* __restrict__ onehot,
                   const int* __restrict__ itr, const int* __restrict__ ite,
                   unsigned short* __restrict__ Thi, unsigned short* __restrict__ Tlo,
                   unsigned short* __restrict__ Qhi, unsigned short* __restrict__ Qlo,
                   float* __restrict__ lab) {
  int gid = blockIdx.x * 256 + threadIdx.x;
  if (gid < NTPAD * NHID) {
    int j = gid >> 7, c = gid & 127;
    unsigned short h = 0, l = 0;
    if (j < NTRAIN) splitbf(emb[(size_t)itr[j] * NHID + c], h, l);
    Thi[gid] = h; Tlo[gid] = l;
  } else if (gid < NTPAD * NHID + NTEST * NHID) {
    int i = gid - NTPAD * NHID;
    int j = i >> 7, c = i & 127;
    unsigned short h, l;
    splitbf(emb[(size_t)ite[j] * NHID + c], h, l);
    Qhi[i] = h; Qlo[i] = l;
  } else if (gid < NTPAD * NHID + NTEST * NHID + NTRAIN * NCLS) {
    int i = gid - NTPAD * NHID - NTEST * NHID;
    int j = i >> 4, c = i & 15;
    lab[i] = onehot[(size_t)itr[j] * NCLS + c];
  }
}

// ---------------- MFMA score tile + per-tile top-20 ----------------
// grid (313, 5). Block: 512 thr = 8 waves; 16 test rows x 1024 train cols.
// Wave w: cols [128w, 128w+128) = 8 col-tiles x (4+8 split-acc MFMA).
// Scores -> swizzled LDS; wave w selects top-20 for rows 2w, 2w+1.
// 64 KB LDS + 512 thr -> 2 blocks/CU = 16 waves/CU (was 8): latency hiding
// for the serial argmax chains; swizzle kills the 4-way write conflicts.
__global__ __launch_bounds__(512)
void score_mfma(const unsigned short* __restrict__ Qhi, const unsigned short* __restrict__ Qlo,
                const unsigned short* __restrict__ Thi, const unsigned short* __restrict__ Tlo,
                float* __restrict__ cand_v, int* __restrict__ cand_i) {
  __shared__ float s[RB * CB];         // 64 KB, swizzled via SWZ
  const int tid = threadIdx.x;
  const int w = tid >> 6, lane = tid & 63;   // w in 0..7
  const int r0 = blockIdx.x * RB;
  const int j0 = blockIdx.y * CB;

  // A fragments: row = r0 + (lane&15), k = 32ks + (lane>>4)*8
  int arow = r0 + (lane & 15); if (arow > NTEST - 1) arow = NTEST - 1;
  const int koff = (lane >> 4) * 8;
  short8v ah[4], al[4];
#pragma unroll
  for (int ks = 0; ks < 4; ++ks) {
    ah[ks] = *reinterpret_cast<const short8v*>(&Qhi[(size_t)arow * 128 + ks * 32 + koff]);
    al[ks] = *reinterpret_cast<const short8v*>(&Qlo[(size_t)arow * 128 + ks * 32 + koff]);
  }

#pragma unroll 2
  for (int t = 0; t < 8; ++t) {
    int colbase = w * 128 + t * 16;
    int col = j0 + colbase + (lane & 15);            // < NTPAD always
    const unsigned short* bh = &Thi[(size_t)col * 128 + koff];
    const unsigned short* bl = &Tlo[(size_t)col * 128 + koff];
    f32x4 a1 = {0.f, 0.f, 0.f, 0.f};                 // hi*hi chain (depth 4)
    f32x4 a2 = {0.f, 0.f, 0.f, 0.f};                 // hi*lo + lo*hi chain (depth 8)
#pragma unroll
    for (int ks = 0; ks < 4; ++ks) {
      short8v bhv = *reinterpret_cast<const short8v*>(&bh[ks * 32]);
      short8v blv = *reinterpret_cast<const short8v*>(&bl[ks * 32]);
      a1 = __builtin_amdgcn_mfma_f32_16x16x32_bf16(ah[ks], bhv, a1, 0, 0, 0);
      a2 = __builtin_amdgcn_mfma_f32_16x16x32_bf16(ah[ks], blv, a2, 0, 0, 0);
      a2 = __builtin_amdgcn_mfma_f32_16x16x32_bf16(al[ks], bhv, a2, 0, 0, 0);
    }
    // C layout: col = lane&15, row = (lane>>4)*4 + r
    int sc = colbase + (lane & 15);
    int sr = (lane >> 4) * 4;
#pragma unroll
    for (int r = 0; r < 4; ++r) s[SWZ(sr + r, sc)] = a1[r] + a2[r];
  }
  __syncthreads();

  // per-wave selection: wave w owns rows 2w, 2w+1
#pragma unroll
  for (int r = 0; r < 2; ++r) {
    const int m = w * 2 + r;
    float v[16];
#pragma unroll
    for (int k = 0; k < 16; ++k) {
      int c = lane + 64 * k;
      v[k] = (j0 + c < NTRAIN) ? s[SWZ(m, c)] : -INFINITY;
    }
    float selv = 0.f; int seli = 0;
#pragma unroll
    for (int it = 0; it < TOPK; ++it) {
      float bv = v[0]; int bk = 0;
#pragma unroll
      for (int k = 1; k < 16; ++k)
        if (v[k] > bv) { bv = v[k]; bk = k; }
      int bj = lane + 64 * bk;
#pragma unroll
      for (int off = 1; off < 64; off <<= 1) {
        float ov = __shfl_xor(bv, off);
        int   oj = __shfl_xor(bj, off);
        if (ov > bv || (ov == bv && oj < bj)) { bv = ov; bj = oj; }
      }
      if (lane == it) { selv = bv; seli = j0 + bj; }
      int ck = bj >> 6;
      if ((bj & 63) == lane) {
#pragma unroll
        for (int k = 0; k < 16; ++k)
          if (k == ck) v[k] = -INFINITY;
      }
    }
    if (lane < TOPK && r0 + m < NTEST) {
      size_t o = ((size_t)(r0 + m) * NJT + blockIdx.y) * TOPK + lane;
      cand_v[o] = selv;
      cand_i[o] = seli;
    }
  }
}

// ---------------- merge candidates + softmax + preds ----------------
__global__ __launch_bounds__(256)
void merge_topk(const float* __restrict__ cand_v, const int* __restrict__ cand_i,
                const float* __restrict__ lab, float* __restrict__ out) {
  const int tid = threadIdx.x;
  const int wv = tid >> 6, lane = tid & 63;
  const int row = blockIdx.x * 4 + wv;
  const size_t base = (size_t)row * (NJT * TOPK);

  float c0 = -INFINITY, c1 = -INFINITY;
  int i0 = 0x7fffffff, i1 = 0x7fffffff;
  if (lane < NJT * TOPK)      { c0 = cand_v[base + lane];      i0 = cand_i[base + lane]; }
  if (lane + 64 < NJT * TOPK) { c1 = cand_v[base + lane + 64]; i1 = cand_i[base + lane + 64]; }

  float selv = 0.f; int seli = 0;
#pragma unroll
  for (int it = 0; it < TOPK; ++it) {
    float bv = c0; int bj = i0;
    if (c1 > bv || (c1 == bv && i1 < bj)) { bv = c1; bj = i1; }
#pragma unroll
    for (int off = 1; off < 64; off <<= 1) {
      float ov = __shfl_xor(bv, off);
      int   oj = __shfl_xor(bj, off);
      if (ov > bv || (ov == bv && oj < bj)) { bv = ov; bj = oj; }
    }
    if (lane == it) { selv = bv; seli = bj; }
    if (i0 == bj) c0 = -INFINITY;
    if (i1 == bj) c1 = -INFINITY;
  }
  float mx = __shfl(selv, 0);
  float wgt = (lane < TOPK) ? expf(selv - mx) : 0.f;
  float sum = wgt;
#pragma unroll
  for (int off = 1; off < 64; off <<= 1) sum += __shfl_xor(sum, off);

  float acc = 0.f;
#pragma unroll
  for (int i = 0; i < TOPK; ++i) {
    float wi = __shfl(wgt, i);
    int   ji = __shfl(seli, i);
    if (lane < NCLS) acc += wi * lab[(size_t)ji * NCLS + lane];
  }
  if (lane < NCLS) out[(size_t)row * NCLS + lane] = acc / sum;
}

extern "C" void kernel_launch(void* const* d_in, const int* in_sizes, int n_in,
                              void* d_out, int out_size, void* d_ws, size_t ws_size,
                              hipStream_t stream) {
  const float* feat   = (const float*)d_in[0];
  const float* ew     = (const float*)d_in[1];
  const float* onehot = (const float*)d_in[2];
  const float* W1     = (const float*)d_in[3];
  const float* b1     = (const float*)d_in[4];
  const float* W2     = (const float*)d_in[5];
  const float* b2     = (const float*)d_in[6];
  const int*   ei     = (const int*)d_in[7];
  const int*   itr    = (const int*)d_in[8];
  const int*   ite    = (const int*)d_in[9];
  float* out = (float*)d_out;
  float* ws  = (float*)d_ws;

  float* bufA   = ws;                                  // [NNODE][128]
  float* bufH   = bufA + (size_t)NNODE * NHID;         // [NNODE][128]
  int*   cursor = (int*)(bufH + (size_t)NNODE * NHID); // [NNODE]
  int2*  packed = (int2*)(cursor + ((NNODE + 15) & ~15)); // [NEDGE]
  // score-phase buffers alias the dead CSR packed region
  unsigned short* Thi = (unsigned short*)packed;                 // [NTPAD][128]
  unsigned short* Tlo = Thi + (size_t)NTPAD * NHID;
  unsigned short* Qhi = Tlo + (size_t)NTPAD * NHID;              // [5000][128]
  unsigned short* Qlo = Qhi + (size_t)NTEST * NHID;
  float* lab = (float*)(Qlo + (size_t)NTEST * NHID);             // [5000][16]
  float* cand_v = bufA;                                // [5000][NJT][20] (bufA dead)
  int*   cand_i = (int*)(bufA + (size_t)NTEST * NJT * TOPK);

  const int* esrc = ei;
  const int* edst = ei + NEDGE;

  // CSR build
  zero_cnt<<<(NNODE + 255) / 256, 256, 0, stream>>>(cursor);
  hist_dst<<<(NEDGE + 255) / 256, 256, 0, stream>>>(edst, cursor);
  scan_cnt<<<1, 256, 0, stream>>>(cursor);
  fill_csr<<<(NEDGE + 255) / 256, 256, 0, stream>>>(esrc, edst, ew, cursor, packed);

  // layer 1 + layer 2
  gemm128<NFEAT, false><<<(NNODE + 63) / 64, 256, 0, stream>>>(feat, W1, bufA, NNODE);
  gather_nodes<<<NNODE / 2, 256, 0, stream>>>(bufA, bufH, cursor, packed, b1);
  gemm128<NHID, true><<<(NNODE + 63) / 64, 256, 0, stream>>>(bufH, W2, bufA, NNODE);
  gather_nodes<<<NNODE / 2, 256, 0, stream>>>(bufA, bufH, cursor, packed, b2);

  // scoring: gather + bf16 split, MFMA score tiles, merge
  int tot = NTPAD * NHID + NTEST * NHID + NTRAIN * NCLS;
  gather_splits<<<(tot + 255) / 256, 256, 0, stream>>>(
      bufH, onehot, itr, ite, Thi, Tlo, Qhi, Qlo, lab);
  score_mfma<<<dim3((NTEST + RB - 1) / RB, NJT), 512, 0, stream>>>(
      Qhi, Qlo, Thi, Tlo, cand_v, cand_i);
  merge_topk<<<NTEST / 4, 256, 0, stream>>>(cand_v, cand_i, lab, out);
}

// Round 6
// 585.696 us; speedup vs baseline: 1.3344x; 1.1737x over previous
//
#include <hip/hip_runtime.h>
#include <math.h>
#include <limits.h>

#define NNODE 50000
#define NEDGE 800000
#define NFEAT 256
#define NHID  128
#define NTEST 5000
#define NTRAIN 5000
#define NCLS  16
#define TOPK  20
#define CB    1024          // cols per score block
#define NJT   5             // col tiles (5120 padded)
#define RB    16            // rows per score block
#define NTPAD (NJT * CB)    // 5120
#define CCAP  640           // per-row candidate cap (5 tiles x 128 max)

typedef __attribute__((ext_vector_type(8))) short short8v;
typedef __attribute__((ext_vector_type(4))) float f32x4;

// swizzled score-LDS index (2-way max on writes and reads; r5 verified conflicts=0)
#define SWZ(r, c) ((r) * CB + (((c) + 4 * (r)) & (CB - 1)))

// ---------------- GEMM: C[M x 128] = op(A)[M x KT] @ B[KT x 128] ----------------
template<int KT, bool RELU>
__global__ __launch_bounds__(256)
void gemm128(const float* __restrict__ A, const float* __restrict__ B,
             float* __restrict__ C, int M) {
  __shared__ float As[32][68];   // [k][m], +4 pad
  __shared__ float Bs[32][128];  // [k][n]
  const int tid = threadIdx.x;
  const int ty = tid >> 4, tx = tid & 15;
  const int m0 = blockIdx.x * 64;
  float acc[4][8];
#pragma unroll
  for (int i = 0; i < 4; ++i)
#pragma unroll
    for (int j = 0; j < 8; ++j) acc[i][j] = 0.f;

  for (int k0 = 0; k0 < KT; k0 += 32) {
#pragma unroll
    for (int p = 0; p < 2; ++p) {
      int li = p * 256 + tid;
      int r  = li >> 3;
      int kc = (li & 7) << 2;
      int gr = m0 + r; if (gr > M - 1) gr = M - 1;
      float4 v = *reinterpret_cast<const float4*>(&A[(size_t)gr * KT + k0 + kc]);
      if (RELU) { v.x=fmaxf(v.x,0.f); v.y=fmaxf(v.y,0.f); v.z=fmaxf(v.z,0.f); v.w=fmaxf(v.w,0.f); }
      As[kc+0][r]=v.x; As[kc+1][r]=v.y; As[kc+2][r]=v.z; As[kc+3][r]=v.w;
    }
#pragma unroll
    for (int p = 0; p < 4; ++p) {
      int li = p * 256 + tid;
      int r  = li >> 5;
      int c4 = (li & 31) << 2;
      *reinterpret_cast<float4*>(&Bs[r][c4]) =
        *reinterpret_cast<const float4*>(&B[(size_t)(k0 + r) * 128 + c4]);
    }
    __syncthreads();
#pragma unroll
    for (int k = 0; k < 32; ++k) {
      float4 a  = *reinterpret_cast<const float4*>(&As[k][ty << 2]);
      float4 b0 = *reinterpret_cast<const float4*>(&Bs[k][tx << 2]);
      float4 b1 = *reinterpret_cast<const float4*>(&Bs[k][64 + (tx << 2)]);
      float av[4] = {a.x, a.y, a.z, a.w};
#pragma unroll
      for (int i = 0; i < 4; ++i) {
        acc[i][0] += av[i]*b0.x; acc[i][1] += av[i]*b0.y;
        acc[i][2] += av[i]*b0.z; acc[i][3] += av[i]*b0.w;
        acc[i][4] += av[i]*b1.x; acc[i][5] += av[i]*b1.y;
        acc[i][6] += av[i]*b1.z; acc[i][7] += av[i]*b1.w;
      }
    }
    __syncthreads();
  }
#pragma unroll
  for (int i = 0; i < 4; ++i) {
    int row = m0 + (ty << 2) + i;
    if (row < M) {
      float4 o0 = {acc[i][0], acc[i][1], acc[i][2], acc[i][3]};
      float4 o1 = {acc[i][4], acc[i][5], acc[i][6], acc[i][7]};
      *reinterpret_cast<float4*>(&C[(size_t)row * 128 + (tx << 2)]) = o0;
      *reinterpret_cast<float4*>(&C[(size_t)row * 128 + 64 + (tx << 2)]) = o1;
    }
  }
}

// ---------------- CSR build ----------------
__global__ __launch_bounds__(256)
void zero_cnt(int* __restrict__ cnt) {
  int i = blockIdx.x * 256 + threadIdx.x;
  if (i < NNODE) cnt[i] = 0;
}

__global__ __launch_bounds__(256)
void hist_dst(const int* __restrict__ edst, int* __restrict__ cnt) {
  int e = blockIdx.x * 256 + threadIdx.x;
  if (e < NEDGE) atomicAdd(&cnt[edst[e]], 1);
}

#define SCHUNK 196
__global__ __launch_bounds__(256)
void scan_cnt(int* __restrict__ cnt) {
  __shared__ int part[256];
  const int t = threadIdx.x;
  const int base = t * SCHUNK;
  int s = 0;
  for (int i = 0; i < SCHUNK; ++i) {
    int idx = base + i;
    if (idx < NNODE) s += cnt[idx];
  }
  part[t] = s;
  __syncthreads();
  for (int off = 1; off < 256; off <<= 1) {
    int v = (t >= off) ? part[t - off] : 0;
    __syncthreads();
    part[t] += v;
    __syncthreads();
  }
  int run = part[t] - s;
  for (int i = 0; i < SCHUNK; ++i) {
    int idx = base + i;
    if (idx < NNODE) { int c = cnt[idx]; cnt[idx] = run; run += c; }
  }
}

__global__ __launch_bounds__(256)
void fill_csr(const int* __restrict__ esrc, const int* __restrict__ edst,
              const float* __restrict__ ew, int* __restrict__ cursor,
              int2* __restrict__ packed) {
  int e = blockIdx.x * 256 + threadIdx.x;
  if (e < NEDGE) {
    int d = edst[e];
    int p = atomicAdd(&cursor[d], 1);
    packed[p] = make_int2(esrc[e], __float_as_int(ew[e]));
  }
}

// ---------------- propagate as gather (4-way edge unroll for MLP) ----------------
__global__ __launch_bounds__(256)
void gather_nodes(const float* __restrict__ X, float* __restrict__ out,
                  const int* __restrict__ endoff, const int2* __restrict__ packed,
                  const float* __restrict__ bias) {
  int node = blockIdx.x * 2 + (threadIdx.x >> 7);
  int c = threadIdx.x & 127;
  int beg = node ? endoff[node - 1] : 0;
  int end = endoff[node];
  float a0 = bias[c], a1 = 0.f, a2 = 0.f, a3 = 0.f;
  int e = beg;
  for (; e + 3 < end; e += 4) {
    int2 p0 = packed[e], p1 = packed[e + 1], p2 = packed[e + 2], p3 = packed[e + 3];
    a0 += __int_as_float(p0.y) * X[(size_t)p0.x * 128 + c];
    a1 += __int_as_float(p1.y) * X[(size_t)p1.x * 128 + c];
    a2 += __int_as_float(p2.y) * X[(size_t)p2.x * 128 + c];
    a3 += __int_as_float(p3.y) * X[(size_t)p3.x * 128 + c];
  }
  for (; e < end; ++e) {
    int2 p = packed[e];
    a0 += __int_as_float(p.y) * X[(size_t)p.x * 128 + c];
  }
  out[(size_t)node * 128 + c] = (a0 + a1) + (a2 + a3);
}

// ---------------- bf16 split helpers ----------------
__device__ inline void splitbf(float x, unsigned short& h, unsigned short& l) {
  unsigned u = __float_as_uint(x);
  unsigned hb = (u + 0x7fffu + ((u >> 16) & 1u)) >> 16;    // RNE to bf16
  float hf = __uint_as_float(hb << 16);
  float r = x - hf;
  unsigned ur = __float_as_uint(r);
  unsigned lb = (ur + 0x7fffu + ((ur >> 16) & 1u)) >> 16;
  h = (unsigned short)hb; l = (unsigned short)lb;
}

// gather + bf16-split + zero per-row candidate counters
__global__ __launch_bounds__(256)
void gather_splits(const float* __restrict__ emb, const float* __restrict__ onehot,
                   const int* __restrict__ itr, const int* __restrict__ ite,
                   unsigned short* __restrict__ Thi, unsigned short* __restrict__ Tlo,
                   unsigned short* __restrict__ Qhi, unsigned short* __restrict__ Qlo,
                   float* __restrict__ lab, int* __restrict__ ccnt) {
  int gid = blockIdx.x * 256 + threadIdx.x;
  if (gid < NTPAD * NHID) {
    int j = gid >> 7, c = gid & 127;
    unsigned short h = 0, l = 0;
    if (j < NTRAIN) splitbf(emb[(size_t)itr[j] * NHID + c], h, l);
    Thi[gid] = h; Tlo[gid] = l;
  } else if (gid < NTPAD * NHID + NTEST * NHID) {
    int i = gid - NTPAD * NHID;
    int j = i >> 7, c = i & 127;
    unsigned short h, l;
    splitbf(emb[(size_t)ite[j] * NHID + c], h, l);
    Qhi[i] = h; Qlo[i] = l;
  } else if (gid < NTPAD * NHID + NTEST * NHID + NTRAIN * NCLS) {
    int i = gid - NTPAD * NHID - NTEST * NHID;
    int j = i >> 4, c = i & 15;
    lab[i] = onehot[(size_t)itr[j] * NCLS + c];
  } else if (gid < NTPAD * NHID + NTEST * NHID + NTRAIN * NCLS + NTEST) {
    ccnt[gid - NTPAD * NHID - NTEST * NHID - NTRAIN * NCLS] = 0;
  }
}

// ---------------- MFMA score tile + threshold-filtered candidate append --------
// grid (313, 5), 512 thr = 8 waves. Wave w: cols [128w,128w+128) via 8x12 MFMA.
// Selection per (row,tile): T = 20th-largest lane-max (value bitonic sort);
// ballot-compact all v >= T (provably contains the tile top-20 SET) into a
// per-row global candidate list. Rare dense case (>128) falls back to exact
// 20x argmax. Set-exact + order-independent => deterministic final output.
__global__ __launch_bounds__(512)
void score_mfma(const unsigned short* __restrict__ Qhi, const unsigned short* __restrict__ Qlo,
                const unsigned short* __restrict__ Thi, const unsigned short* __restrict__ Tlo,
                int* __restrict__ ccnt, float* __restrict__ candv, int* __restrict__ candi) {
  __shared__ float s[RB * CB];         // 64 KB, swizzled via SWZ
  const int tid = threadIdx.x;
  const int w = tid >> 6, lane = tid & 63;   // w in 0..7
  const int r0 = blockIdx.x * RB;
  const int j0 = blockIdx.y * CB;

  // A fragments: row = r0 + (lane&15), k = 32ks + (lane>>4)*8
  int arow = r0 + (lane & 15); if (arow > NTEST - 1) arow = NTEST - 1;
  const int koff = (lane >> 4) * 8;
  short8v ah[4], al[4];
#pragma unroll
  for (int ks = 0; ks < 4; ++ks) {
    ah[ks] = *reinterpret_cast<const short8v*>(&Qhi[(size_t)arow * 128 + ks * 32 + koff]);
    al[ks] = *reinterpret_cast<const short8v*>(&Qlo[(size_t)arow * 128 + ks * 32 + koff]);
  }

#pragma unroll 2
  for (int t = 0; t < 8; ++t) {
    int colbase = w * 128 + t * 16;
    int col = j0 + colbase + (lane & 15);            // < NTPAD always
    const unsigned short* bh = &Thi[(size_t)col * 128 + koff];
    const unsigned short* bl = &Tlo[(size_t)col * 128 + koff];
    f32x4 a1 = {0.f, 0.f, 0.f, 0.f};
    f32x4 a2 = {0.f, 0.f, 0.f, 0.f};
#pragma unroll
    for (int ks = 0; ks < 4; ++ks) {
      short8v bhv = *reinterpret_cast<const short8v*>(&bh[ks * 32]);
      short8v blv = *reinterpret_cast<const short8v*>(&bl[ks * 32]);
      a1 = __builtin_amdgcn_mfma_f32_16x16x32_bf16(ah[ks], bhv, a1, 0, 0, 0);
      a2 = __builtin_amdgcn_mfma_f32_16x16x32_bf16(ah[ks], blv, a2, 0, 0, 0);
      a2 = __builtin_amdgcn_mfma_f32_16x16x32_bf16(al[ks], bhv, a2, 0, 0, 0);
    }
    int sc = colbase + (lane & 15);
    int sr = (lane >> 4) * 4;
#pragma unroll
    for (int r = 0; r < 4; ++r) s[SWZ(sr + r, sc)] = a1[r] + a2[r];
  }
  __syncthreads();

  const unsigned long long ltm = ((unsigned long long)1 << lane) - 1;

  // per-wave selection: wave w owns rows 2w, 2w+1
#pragma unroll
  for (int r = 0; r < 2; ++r) {
    const int m = w * 2 + r;
    const int row = r0 + m;
    if (row >= NTEST) continue;
    float v[16];
#pragma unroll
    for (int k = 0; k < 16; ++k) {
      int c = lane + 64 * k;
      v[k] = (j0 + c < NTRAIN) ? s[SWZ(m, c)] : -INFINITY;
    }
    // lane max (tree)
    float t0 = fmaxf(v[0], v[1]),  t1 = fmaxf(v[2], v[3]);
    float t2 = fmaxf(v[4], v[5]),  t3 = fmaxf(v[6], v[7]);
    float t4 = fmaxf(v[8], v[9]),  t5 = fmaxf(v[10], v[11]);
    float t6 = fmaxf(v[12], v[13]), t7 = fmaxf(v[14], v[15]);
    float sv = fmaxf(fmaxf(fmaxf(t0, t1), fmaxf(t2, t3)),
                     fmaxf(fmaxf(t4, t5), fmaxf(t6, t7)));
    // bitonic sort (desc) of the 64 lane-maxes, values only
#pragma unroll
    for (int k = 2; k <= 64; k <<= 1) {
#pragma unroll
      for (int j = k >> 1; j > 0; j >>= 1) {
        float ov = __shfl_xor(sv, j);
        bool keepMax = ((lane & j) == 0) == ((lane & k) == 0 || k == 64);
        sv = keepMax ? fmaxf(sv, ov) : fminf(sv, ov);
      }
    }
    float T = __shfl(sv, 19);       // 20th-largest lane-max

    int myo[16];
    int tot = 0;
#pragma unroll
    for (int k = 0; k < 16; ++k) {
      unsigned long long mk = __ballot(v[k] >= T);
      myo[k] = tot + (int)__popcll(mk & ltm);
      tot += (int)__popcll(mk);
    }
    if (tot <= 128) {               // fast path (typical tot ~ 25)
      int base = 0;
      if (lane == 0) base = atomicAdd(&ccnt[row], tot);
      base = __shfl(base, 0);
      float* cv = candv + (size_t)row * CCAP + base;
      int*   ci = candi + (size_t)row * CCAP + base;
#pragma unroll
      for (int k = 0; k < 16; ++k) {
        if (v[k] >= T) { cv[myo[k]] = v[k]; ci[myo[k]] = j0 + lane + 64 * k; }
      }
    } else {                        // rare dense path: exact top-20, append 20
      float selv = 0.f; int seli = 0;
#pragma unroll
      for (int it = 0; it < TOPK; ++it) {
        float bv = v[0]; int bk = 0;
#pragma unroll
        for (int k = 1; k < 16; ++k)
          if (v[k] > bv) { bv = v[k]; bk = k; }
        int bj = lane + 64 * bk;
#pragma unroll
        for (int off = 1; off < 64; off <<= 1) {
          float ov = __shfl_xor(bv, off);
          int   oj = __shfl_xor(bj, off);
          if (ov > bv || (ov == bv && oj < bj)) { bv = ov; bj = oj; }
        }
        if (lane == it) { selv = bv; seli = j0 + bj; }
        int ck = bj >> 6;
        if ((bj & 63) == lane) {
#pragma unroll
          for (int k = 0; k < 16; ++k)
            if (k == ck) v[k] = -INFINITY;
        }
      }
      int base = 0;
      if (lane == 0) base = atomicAdd(&ccnt[row], TOPK);
      base = __shfl(base, 0);
      if (lane < TOPK) {
        candv[(size_t)row * CCAP + base + lane] = selv;
        candi[(size_t)row * CCAP + base + lane] = seli;
      }
    }
  }
}

// 64-lane bitonic sort, descending by (value, then ascending index)
__device__ inline void sort64_vi(float& v, int& idx, int lane) {
#pragma unroll
  for (int k = 2; k <= 64; k <<= 1) {
#pragma unroll
    for (int j = k >> 1; j > 0; j >>= 1) {
      float ov = __shfl_xor(v, j);
      int   oi = __shfl_xor(idx, j);
      bool first = (v > ov) || (v == ov && idx < oi);
      bool keepMine = (((lane & j) == 0) == ((lane & k) == 0 || k == 64)) ? first : !first;
      if (!keepMine) { v = ov; idx = oi; }
    }
  }
}

// ---------------- merge: streaming bitonic top-20 + softmax + preds ----------
__global__ __launch_bounds__(256)
void merge_topk(const float* __restrict__ candv, const int* __restrict__ candi,
                const int* __restrict__ ccnt, const float* __restrict__ lab,
                float* __restrict__ out) {
  const int tid = threadIdx.x;
  const int wv = tid >> 6, lane = tid & 63;
  const int row = blockIdx.x * 4 + wv;
  const size_t base = (size_t)row * CCAP;
  const int C = ccnt[row];

  float v = -INFINITY; int idx = INT_MAX;
  int take = C < 64 ? C : 64;
  if (lane < take) { v = candv[base + lane]; idx = candi[base + lane]; }
  sort64_vi(v, idx, lane);
  int consumed = take;
  while (consumed < C) {
    int n = C - consumed; if (n > 44) n = 44;
    if (lane >= TOPK) {
      int p = lane - TOPK;
      if (p < n) { v = candv[base + consumed + p]; idx = candi[base + consumed + p]; }
      else       { v = -INFINITY; idx = INT_MAX; }
    }
    sort64_vi(v, idx, lane);
    consumed += n;
  }
  // lanes 0..19 hold the exact top-20 (desc); softmax + label accumulate
  float mx = __shfl(v, 0);
  float wgt = (lane < TOPK) ? expf(v - mx) : 0.f;
  float sum = wgt;
#pragma unroll
  for (int off = 1; off < 64; off <<= 1) sum += __shfl_xor(sum, off);

  float acc = 0.f;
#pragma unroll
  for (int i = 0; i < TOPK; ++i) {
    float wi = __shfl(wgt, i);
    int   ji = __shfl(idx, i);
    if (lane < NCLS) acc += wi * lab[(size_t)ji * NCLS + lane];
  }
  if (lane < NCLS) out[(size_t)row * NCLS + lane] = acc / sum;
}

extern "C" void kernel_launch(void* const* d_in, const int* in_sizes, int n_in,
                              void* d_out, int out_size, void* d_ws, size_t ws_size,
                              hipStream_t stream) {
  const float* feat   = (const float*)d_in[0];
  const float* ew     = (const float*)d_in[1];
  const float* onehot = (const float*)d_in[2];
  const float* W1     = (const float*)d_in[3];
  const float* b1     = (const float*)d_in[4];
  const float* W2     = (const float*)d_in[5];
  const float* b2     = (const float*)d_in[6];
  const int*   ei     = (const int*)d_in[7];
  const int*   itr    = (const int*)d_in[8];
  const int*   ite    = (const int*)d_in[9];
  float* out = (float*)d_out;
  float* ws  = (float*)d_ws;

  float* bufA   = ws;                                  // [NNODE][128]
  float* bufH   = bufA + (size_t)NNODE * NHID;         // [NNODE][128]
  int*   cursor = (int*)(bufH + (size_t)NNODE * NHID); // [NNODE]
  int2*  packed = (int2*)(cursor + ((NNODE + 15) & ~15)); // [NEDGE]
  // score-phase buffers alias the dead CSR packed region (5.5MB + 20KB < 6.4MB)
  unsigned short* Thi = (unsigned short*)packed;                 // [NTPAD][128]
  unsigned short* Tlo = Thi + (size_t)NTPAD * NHID;
  unsigned short* Qhi = Tlo + (size_t)NTPAD * NHID;              // [5000][128]
  unsigned short* Qlo = Qhi + (size_t)NTEST * NHID;
  float* lab  = (float*)(Qlo + (size_t)NTEST * NHID);            // [5000][16]
  int*   ccnt = (int*)(lab + (size_t)NTRAIN * NCLS);             // [5000]
  // candidate lists alias bufA (dead after second gather): 5000*640*(4+4)B = 25.6MB
  float* candv = bufA;
  int*   candi = (int*)(bufA + (size_t)NTEST * CCAP);

  const int* esrc = ei;
  const int* edst = ei + NEDGE;

  // CSR build
  zero_cnt<<<(NNODE + 255) / 256, 256, 0, stream>>>(cursor);
  hist_dst<<<(NEDGE + 255) / 256, 256, 0, stream>>>(edst, cursor);
  scan_cnt<<<1, 256, 0, stream>>>(cursor);
  fill_csr<<<(NEDGE + 255) / 256, 256, 0, stream>>>(esrc, edst, ew, cursor, packed);

  // layer 1 + layer 2
  gemm128<NFEAT, false><<<(NNODE + 63) / 64, 256, 0, stream>>>(feat, W1, bufA, NNODE);
  gather_nodes<<<NNODE / 2, 256, 0, stream>>>(bufA, bufH, cursor, packed, b1);
  gemm128<NHID, true><<<(NNODE + 63) / 64, 256, 0, stream>>>(bufH, W2, bufA, NNODE);
  gather_nodes<<<NNODE / 2, 256, 0, stream>>>(bufA, bufH, cursor, packed, b2);

  // scoring: gather + bf16 split (+ccnt zero), MFMA score + candidate filter, merge
  int tot = NTPAD * NHID + NTEST * NHID + NTRAIN * NCLS + NTEST;
  gather_splits<<<(tot + 255) / 256, 256, 0, stream>>>(
      bufH, onehot, itr, ite, Thi, Tlo, Qhi, Qlo, lab, ccnt);
  score_mfma<<<dim3((NTEST + RB - 1) / RB, NJT), 512, 0, stream>>>(
      Qhi, Qlo, Thi, Tlo, ccnt, candv, candi);
  merge_topk<<<NTEST / 4, 256, 0, stream>>>(candv, candi, ccnt, lab, out);
}

// Round 7
// 499.598 us; speedup vs baseline: 1.5643x; 1.1723x over previous
//
#include <hip/hip_runtime.h>
#include <math.h>
#include <limits.h>

#define NNODE 50000
#define NEDGE 800000
#define NFEAT 256
#define NHID  128
#define NTEST 5000
#define NTRAIN 5000
#define NCLS  16
#define TOPK  20
#define CB    512           // cols per score block (32KB LDS -> 4 blocks/CU)
#define NCT   10            // col tiles (5120 padded)
#define RB    16            // rows per score block
#define NTPAD (NCT * CB)    // 5120
#define CCAP  1280          // per-row candidate cap (10 tiles x 128 max)

typedef __attribute__((ext_vector_type(8))) short short8v;
typedef __attribute__((ext_vector_type(4))) float f32x4;

// swizzled score-LDS index (2-way max on writes and reads)
#define SWZ(r, c) ((r) * CB + (((c) + 4 * (r)) & (CB - 1)))

// ---------------- bf16 split helpers ----------------
__device__ inline void splitbf(float x, unsigned short& h, unsigned short& l) {
  unsigned u = __float_as_uint(x);
  unsigned hb = (u + 0x7fffu + ((u >> 16) & 1u)) >> 16;    // RNE to bf16
  float hf = __uint_as_float(hb << 16);
  float r = x - hf;
  unsigned ur = __float_as_uint(r);
  unsigned lb = (ur + 0x7fffu + ((ur >> 16) & 1u)) >> 16;
  h = (unsigned short)hb; l = (unsigned short)lb;
}

__device__ inline void split8(float4 a0, float4 a1, short8v& h, short8v& l) {
  unsigned short hh, ll;
  splitbf(a0.x, hh, ll); h[0] = (short)hh; l[0] = (short)ll;
  splitbf(a0.y, hh, ll); h[1] = (short)hh; l[1] = (short)ll;
  splitbf(a0.z, hh, ll); h[2] = (short)hh; l[2] = (short)ll;
  splitbf(a0.w, hh, ll); h[3] = (short)hh; l[3] = (short)ll;
  splitbf(a1.x, hh, ll); h[4] = (short)hh; l[4] = (short)ll;
  splitbf(a1.y, hh, ll); h[5] = (short)hh; l[5] = (short)ll;
  splitbf(a1.z, hh, ll); h[6] = (short)hh; l[6] = (short)ll;
  splitbf(a1.w, hh, ll); h[7] = (short)hh; l[7] = (short)ll;
}

// split W[K][128] -> WThi/WTlo [128][K] (transposed so B-frags are contiguous)
__global__ __launch_bounds__(256)
void split_w(const float* __restrict__ W, int KT,
             unsigned short* __restrict__ hi, unsigned short* __restrict__ lo) {
  int gid = blockIdx.x * 256 + threadIdx.x;
  if (gid < KT * 128) {
    int n = gid / KT, k = gid - n * KT;
    unsigned short h, l;
    splitbf(W[(size_t)k * 128 + n], h, l);
    hi[gid] = h; lo[gid] = l;
  }
}

// ---------------- MFMA GEMM: C[M x 128] = op(A)[M x KT] @ W ----------------
// 256 thr = 4 waves; BM=64 (16 rows/wave); A fp32 split in-reg; B from
// pre-split WT (L1/L2-hot). 3-term bf16 split, fused single acc chain.
template<int KT, bool RELU>
__global__ __launch_bounds__(256)
void gemm_mfma(const float* __restrict__ A, const unsigned short* __restrict__ WThi,
               const unsigned short* __restrict__ WTlo, float* __restrict__ C, int M) {
  const int tid = threadIdx.x;
  const int w = tid >> 6, lane = tid & 63;
  const int m0 = blockIdx.x * 64 + w * 16;
  int arow = m0 + (lane & 15); if (arow > M - 1) arow = M - 1;
  const int koff = (lane >> 4) * 8;

  f32x4 acc[8];
#pragma unroll
  for (int t = 0; t < 8; ++t) acc[t] = {0.f, 0.f, 0.f, 0.f};

#pragma unroll
  for (int ks = 0; ks < KT / 32; ++ks) {
    const float* ap = &A[(size_t)arow * KT + ks * 32 + koff];
    float4 a0 = *reinterpret_cast<const float4*>(ap);
    float4 a1 = *reinterpret_cast<const float4*>(ap + 4);
    if (RELU) {
      a0.x=fmaxf(a0.x,0.f); a0.y=fmaxf(a0.y,0.f); a0.z=fmaxf(a0.z,0.f); a0.w=fmaxf(a0.w,0.f);
      a1.x=fmaxf(a1.x,0.f); a1.y=fmaxf(a1.y,0.f); a1.z=fmaxf(a1.z,0.f); a1.w=fmaxf(a1.w,0.f);
    }
    short8v ah, al;
    split8(a0, a1, ah, al);
#pragma unroll
    for (int t = 0; t < 8; ++t) {
      size_t bo = (size_t)(t * 16 + (lane & 15)) * KT + ks * 32 + koff;
      short8v bh = *reinterpret_cast<const short8v*>(&WThi[bo]);
      short8v bl = *reinterpret_cast<const short8v*>(&WTlo[bo]);
      acc[t] = __builtin_amdgcn_mfma_f32_16x16x32_bf16(ah, bh, acc[t], 0, 0, 0);
      acc[t] = __builtin_amdgcn_mfma_f32_16x16x32_bf16(ah, bl, acc[t], 0, 0, 0);
      acc[t] = __builtin_amdgcn_mfma_f32_16x16x32_bf16(al, bh, acc[t], 0, 0, 0);
    }
  }
  // C layout: col = lane&15, row = (lane>>4)*4 + j
  const int crow0 = m0 + (lane >> 4) * 4;
#pragma unroll
  for (int j = 0; j < 4; ++j) {
    int row = crow0 + j;
    if (row < M) {
#pragma unroll
      for (int t = 0; t < 8; ++t)
        C[(size_t)row * 128 + t * 16 + (lane & 15)] = acc[t][j];
    }
  }
}

// ---------------- CSR build ----------------
__global__ __launch_bounds__(256)
void zero_cnt(int* __restrict__ cnt) {
  int i = blockIdx.x * 256 + threadIdx.x;
  if (i < NNODE) cnt[i] = 0;
}

__global__ __launch_bounds__(256)
void hist_dst(const int* __restrict__ edst, int* __restrict__ cnt) {
  int e = blockIdx.x * 256 + threadIdx.x;
  if (e < NEDGE) atomicAdd(&cnt[edst[e]], 1);
}

#define SCHUNK 196
__global__ __launch_bounds__(256)
void scan_cnt(int* __restrict__ cnt) {
  __shared__ int part[256];
  const int t = threadIdx.x;
  const int base = t * SCHUNK;
  int s = 0;
  for (int i = 0; i < SCHUNK / 4; ++i) {
    int idx = base + i * 4;
    if (idx + 3 < NNODE) {
      int4 v = *reinterpret_cast<const int4*>(&cnt[idx]);
      s += v.x + v.y + v.z + v.w;
    } else {
      for (int j = 0; j < 4; ++j) if (idx + j < NNODE) s += cnt[idx + j];
    }
  }
  part[t] = s;
  __syncthreads();
  for (int off = 1; off < 256; off <<= 1) {
    int v = (t >= off) ? part[t - off] : 0;
    __syncthreads();
    part[t] += v;
    __syncthreads();
  }
  int run = part[t] - s;
  for (int i = 0; i < SCHUNK / 4; ++i) {
    int idx = base + i * 4;
    if (idx + 3 < NNODE) {
      int4 v = *reinterpret_cast<const int4*>(&cnt[idx]);
      int4 o;
      o.x = run; run += v.x; o.y = run; run += v.y;
      o.z = run; run += v.z; o.w = run; run += v.w;
      *reinterpret_cast<int4*>(&cnt[idx]) = o;
    } else {
      for (int j = 0; j < 4; ++j)
        if (idx + j < NNODE) { int c = cnt[idx + j]; cnt[idx + j] = run; run += c; }
    }
  }
}

__global__ __launch_bounds__(256)
void fill_csr(const int* __restrict__ esrc, const int* __restrict__ edst,
              const float* __restrict__ ew, int* __restrict__ cursor,
              int2* __restrict__ packed) {
  int e = blockIdx.x * 256 + threadIdx.x;
  if (e < NEDGE) {
    int d = edst[e];
    int p = atomicAdd(&cursor[d], 1);
    packed[p] = make_int2(esrc[e], __float_as_int(ew[e]));
  }
}

// ---------------- propagate as gather (float2/lane, 4 nodes/block) ----------
__global__ __launch_bounds__(256)
void gather_nodes(const float* __restrict__ X, float* __restrict__ out,
                  const int* __restrict__ endoff, const int2* __restrict__ packed,
                  const float* __restrict__ bias) {
  int node = blockIdx.x * 4 + (threadIdx.x >> 6);
  int c2 = threadIdx.x & 63;                       // float2 channel index
  int beg = node ? endoff[node - 1] : 0;
  int end = endoff[node];
  const float2* X2 = reinterpret_cast<const float2*>(X);
  float2 a0 = reinterpret_cast<const float2*>(bias)[c2];
  float2 a1 = {0.f, 0.f}, a2 = {0.f, 0.f}, a3 = {0.f, 0.f};
  int e = beg;
  for (; e + 3 < end; e += 4) {
    int2 p0 = packed[e], p1 = packed[e + 1], p2 = packed[e + 2], p3 = packed[e + 3];
    float2 x0 = X2[(size_t)p0.x * 64 + c2];
    float2 x1 = X2[(size_t)p1.x * 64 + c2];
    float2 x2 = X2[(size_t)p2.x * 64 + c2];
    float2 x3 = X2[(size_t)p3.x * 64 + c2];
    float w0 = __int_as_float(p0.y), w1 = __int_as_float(p1.y);
    float w2 = __int_as_float(p2.y), w3 = __int_as_float(p3.y);
    a0.x += w0 * x0.x; a0.y += w0 * x0.y;
    a1.x += w1 * x1.x; a1.y += w1 * x1.y;
    a2.x += w2 * x2.x; a2.y += w2 * x2.y;
    a3.x += w3 * x3.x; a3.y += w3 * x3.y;
  }
  for (; e < end; ++e) {
    int2 p = packed[e];
    float2 x = X2[(size_t)p.x * 64 + c2];
    float w = __int_as_float(p.y);
    a0.x += w * x.x; a0.y += w * x.y;
  }
  float2 r;
  r.x = (a0.x + a1.x) + (a2.x + a3.x);
  r.y = (a0.y + a1.y) + (a2.y + a3.y);
  reinterpret_cast<float2*>(out)[(size_t)node * 64 + c2] = r;
}

// ---------------- gather + bf16-split + zero candidate counters --------------
__global__ __launch_bounds__(256)
void gather_splits(const float* __restrict__ emb, const float* __restrict__ onehot,
                   const int* __restrict__ itr, const int* __restrict__ ite,
                   unsigned short* __restrict__ Thi, unsigned short* __restrict__ Tlo,
                   unsigned short* __restrict__ Qhi, unsigned short* __restrict__ Qlo,
                   float* __restrict__ lab, int* __restrict__ ccnt) {
  int gid = blockIdx.x * 256 + threadIdx.x;
  if (gid < NTPAD * NHID) {
    int j = gid >> 7, c = gid & 127;
    unsigned short h = 0, l = 0;
    if (j < NTRAIN) splitbf(emb[(size_t)itr[j] * NHID + c], h, l);
    Thi[gid] = h; Tlo[gid] = l;
  } else if (gid < NTPAD * NHID + NTEST * NHID) {
    int i = gid - NTPAD * NHID;
    int j = i >> 7, c = i & 127;
    unsigned short h, l;
    splitbf(emb[(size_t)ite[j] * NHID + c], h, l);
    Qhi[i] = h; Qlo[i] = l;
  } else if (gid < NTPAD * NHID + NTEST * NHID + NTRAIN * NCLS) {
    int i = gid - NTPAD * NHID - NTEST * NHID;
    int j = i >> 4, c = i & 15;
    lab[i] = onehot[(size_t)itr[j] * NCLS + c];
  } else if (gid < NTPAD * NHID + NTEST * NHID + NTRAIN * NCLS + NTEST) {
    ccnt[gid - NTPAD * NHID - NTEST * NHID - NTRAIN * NCLS] = 0;
  }
}

// ---------------- MFMA score tile + threshold-filtered candidate append ------
// grid (313, 10), 512 thr = 8 waves. Wave w: cols [64w,64w+64) = 4 tiles x 12
// MFMA (single fused acc chain, VGPR-lean). Scores -> swizzled 32KB LDS;
// selection: T = 20th-largest lane-max via value bitonic; ballot-compact
// v >= T (set contains tile top-20); dense fallback = exact argmax x20.
__global__ __launch_bounds__(512)
void score_mfma(const unsigned short* __restrict__ Qhi, const unsigned short* __restrict__ Qlo,
                const unsigned short* __restrict__ Thi, const unsigned short* __restrict__ Tlo,
                int* __restrict__ ccnt, float* __restrict__ candv, int* __restrict__ candi) {
  __shared__ float s[RB * CB];         // 32 KB
  const int tid = threadIdx.x;
  const int w = tid >> 6, lane = tid & 63;   // w in 0..7
  const int r0 = blockIdx.x * RB;
  const int j0 = blockIdx.y * CB;

  int arow = r0 + (lane & 15); if (arow > NTEST - 1) arow = NTEST - 1;
  const int koff = (lane >> 4) * 8;
  short8v ah[4], al[4];
#pragma unroll
  for (int ks = 0; ks < 4; ++ks) {
    ah[ks] = *reinterpret_cast<const short8v*>(&Qhi[(size_t)arow * 128 + ks * 32 + koff]);
    al[ks] = *reinterpret_cast<const short8v*>(&Qlo[(size_t)arow * 128 + ks * 32 + koff]);
  }

#pragma unroll 2
  for (int t = 0; t < 4; ++t) {
    int colbase = w * 64 + t * 16;
    int col = j0 + colbase + (lane & 15);            // < NTPAD always
    const unsigned short* bh = &Thi[(size_t)col * 128 + koff];
    const unsigned short* bl = &Tlo[(size_t)col * 128 + koff];
    f32x4 a = {0.f, 0.f, 0.f, 0.f};
#pragma unroll
    for (int ks = 0; ks < 4; ++ks) {
      short8v bhv = *reinterpret_cast<const short8v*>(&bh[ks * 32]);
      short8v blv = *reinterpret_cast<const short8v*>(&bl[ks * 32]);
      a = __builtin_amdgcn_mfma_f32_16x16x32_bf16(ah[ks], bhv, a, 0, 0, 0);
      a = __builtin_amdgcn_mfma_f32_16x16x32_bf16(ah[ks], blv, a, 0, 0, 0);
      a = __builtin_amdgcn_mfma_f32_16x16x32_bf16(al[ks], bhv, a, 0, 0, 0);
    }
    int sc = colbase + (lane & 15);
    int sr = (lane >> 4) * 4;
#pragma unroll
    for (int r = 0; r < 4; ++r) s[SWZ(sr + r, sc)] = a[r];
  }
  __syncthreads();

  const unsigned long long ltm = ((unsigned long long)1 << lane) - 1;

#pragma unroll
  for (int r = 0; r < 2; ++r) {
    const int m = w * 2 + r;
    const int row = r0 + m;
    if (row >= NTEST) continue;
    float v[8];
#pragma unroll
    for (int k = 0; k < 8; ++k) {
      int c = lane + 64 * k;
      v[k] = (j0 + c < NTRAIN) ? s[SWZ(m, c)] : -INFINITY;
    }
    // lane max (tree)
    float t0 = fmaxf(v[0], v[1]), t1 = fmaxf(v[2], v[3]);
    float t2 = fmaxf(v[4], v[5]), t3 = fmaxf(v[6], v[7]);
    float sv = fmaxf(fmaxf(t0, t1), fmaxf(t2, t3));
    // bitonic sort (desc) of 64 lane-maxes, values only
#pragma unroll
    for (int k = 2; k <= 64; k <<= 1) {
#pragma unroll
      for (int j = k >> 1; j > 0; j >>= 1) {
        float ov = __shfl_xor(sv, j);
        bool keepMax = ((lane & j) == 0) == ((lane & k) == 0 || k == 64);
        sv = keepMax ? fmaxf(sv, ov) : fminf(sv, ov);
      }
    }
    float T = __shfl(sv, 19);       // 20th-largest lane-max

    int myo[8];
    int tot = 0;
#pragma unroll
    for (int k = 0; k < 8; ++k) {
      unsigned long long mk = __ballot(v[k] >= T);
      myo[k] = tot + (int)__popcll(mk & ltm);
      tot += (int)__popcll(mk);
    }
    if (tot <= 128) {               // typical tot ~ 22
      int base = 0;
      if (lane == 0) base = atomicAdd(&ccnt[row], tot);
      base = __shfl(base, 0);
      float* cv = candv + (size_t)row * CCAP + base;
      int*   ci = candi + (size_t)row * CCAP + base;
#pragma unroll
      for (int k = 0; k < 8; ++k) {
        if (v[k] >= T) { cv[myo[k]] = v[k]; ci[myo[k]] = j0 + lane + 64 * k; }
      }
    } else {                        // rare dense path: exact top-20
      float selv = 0.f; int seli = 0;
#pragma unroll
      for (int it = 0; it < TOPK; ++it) {
        float bv = v[0]; int bk = 0;
#pragma unroll
        for (int k = 1; k < 8; ++k)
          if (v[k] > bv) { bv = v[k]; bk = k; }
        int bj = lane + 64 * bk;
#pragma unroll
        for (int off = 1; off < 64; off <<= 1) {
          float ov = __shfl_xor(bv, off);
          int   oj = __shfl_xor(bj, off);
          if (ov > bv || (ov == bv && oj < bj)) { bv = ov; bj = oj; }
        }
        if (lane == it) { selv = bv; seli = j0 + bj; }
        int ck = bj >> 6;
        if ((bj & 63) == lane) {
#pragma unroll
          for (int k = 0; k < 8; ++k)
            if (k == ck) v[k] = -INFINITY;
        }
      }
      int base = 0;
      if (lane == 0) base = atomicAdd(&ccnt[row], TOPK);
      base = __shfl(base, 0);
      if (lane < TOPK) {
        candv[(size_t)row * CCAP + base + lane] = selv;
        candi[(size_t)row * CCAP + base + lane] = seli;
      }
    }
  }
}

// 64-lane bitonic sort, descending by (value, then ascending index)
__device__ inline void sort64_vi(float& v, int& idx, int lane) {
#pragma unroll
  for (int k = 2; k <= 64; k <<= 1) {
#pragma unroll
    for (int j = k >> 1; j > 0; j >>= 1) {
      float ov = __shfl_xor(v, j);
      int   oi = __shfl_xor(idx, j);
      bool first = (v > ov) || (v == ov && idx < oi);
      bool keepMine = (((lane & j) == 0) == ((lane & k) == 0 || k == 64)) ? first : !first;
      if (!keepMine) { v = ov; idx = oi; }
    }
  }
}

// ---------------- merge: streaming bitonic top-20 + softmax + preds ----------
__global__ __launch_bounds__(256)
void merge_topk(const float* __restrict__ candv, const int* __restrict__ candi,
                const int* __restrict__ ccnt, const float* __restrict__ lab,
                float* __restrict__ out) {
  const int tid = threadIdx.x;
  const int wv = tid >> 6, lane = tid & 63;
  const int row = blockIdx.x * 4 + wv;
  const size_t base = (size_t)row * CCAP;
  const int C = ccnt[row];

  float v = -INFINITY; int idx = INT_MAX;
  int take = C < 64 ? C : 64;
  if (lane < take) { v = candv[base + lane]; idx = candi[base + lane]; }
  sort64_vi(v, idx, lane);
  int consumed = take;
  while (consumed < C) {
    int n = C - consumed; if (n > 44) n = 44;
    if (lane >= TOPK) {
      int p = lane - TOPK;
      if (p < n) { v = candv[base + consumed + p]; idx = candi[base + consumed + p]; }
      else       { v = -INFINITY; idx = INT_MAX; }
    }
    sort64_vi(v, idx, lane);
    consumed += n;
  }
  float mx = __shfl(v, 0);
  float wgt = (lane < TOPK) ? expf(v - mx) : 0.f;
  float sum = wgt;
#pragma unroll
  for (int off = 1; off < 64; off <<= 1) sum += __shfl_xor(sum, off);

  float acc = 0.f;
#pragma unroll
  for (int i = 0; i < TOPK; ++i) {
    float wi = __shfl(wgt, i);
    int   ji = __shfl(idx, i);
    if (lane < NCLS) acc += wi * lab[(size_t)ji * NCLS + lane];
  }
  if (lane < NCLS) out[(size_t)row * NCLS + lane] = acc / sum;
}

extern "C" void kernel_launch(void* const* d_in, const int* in_sizes, int n_in,
                              void* d_out, int out_size, void* d_ws, size_t ws_size,
                              hipStream_t stream) {
  const float* feat   = (const float*)d_in[0];
  const float* ew     = (const float*)d_in[1];
  const float* onehot = (const float*)d_in[2];
  const float* W1     = (const float*)d_in[3];
  const float* b1     = (const float*)d_in[4];
  const float* W2     = (const float*)d_in[5];
  const float* b2     = (const float*)d_in[6];
  const int*   ei     = (const int*)d_in[7];
  const int*   itr    = (const int*)d_in[8];
  const int*   ite    = (const int*)d_in[9];
  float* out = (float*)d_out;
  float* ws  = (float*)d_ws;

  float* bufA   = ws;                                  // [NNODE][128]
  float* bufH   = bufA + (size_t)NNODE * NHID;         // [NNODE][128]
  int*   cursor = (int*)(bufH + (size_t)NNODE * NHID); // [NNODE]
  int2*  packed = (int2*)(cursor + ((NNODE + 15) & ~15)); // [NEDGE]
  // pre-split transposed weights, after packed (alive through gemm2)
  unsigned short* WT1hi = (unsigned short*)(packed + NEDGE);    // [128][256]
  unsigned short* WT1lo = WT1hi + 128 * NFEAT;
  unsigned short* WT2hi = WT1lo + 128 * NFEAT;                  // [128][128]
  unsigned short* WT2lo = WT2hi + 128 * NHID;
  // score-phase buffers alias the dead CSR packed region
  unsigned short* Thi = (unsigned short*)packed;                // [NTPAD][128]
  unsigned short* Tlo = Thi + (size_t)NTPAD * NHID;
  unsigned short* Qhi = Tlo + (size_t)NTPAD * NHID;             // [5000][128]
  unsigned short* Qlo = Qhi + (size_t)NTEST * NHID;
  float* lab  = (float*)(Qlo + (size_t)NTEST * NHID);           // [5000][16]
  int*   ccnt = (int*)(lab + (size_t)NTRAIN * NCLS);            // [5000]
  // candidate lists alias bufA/bufH (dead after gather_splits): 5000*1280 each
  float* candv = bufA;
  int*   candi = (int*)bufH;

  const int* esrc = ei;
  const int* edst = ei + NEDGE;

  // CSR build + weight split
  zero_cnt<<<(NNODE + 255) / 256, 256, 0, stream>>>(cursor);
  hist_dst<<<(NEDGE + 255) / 256, 256, 0, stream>>>(edst, cursor);
  scan_cnt<<<1, 256, 0, stream>>>(cursor);
  fill_csr<<<(NEDGE + 255) / 256, 256, 0, stream>>>(esrc, edst, ew, cursor, packed);
  split_w<<<(NFEAT * 128 + 255) / 256, 256, 0, stream>>>(W1, NFEAT, WT1hi, WT1lo);
  split_w<<<(NHID * 128 + 255) / 256, 256, 0, stream>>>(W2, NHID, WT2hi, WT2lo);

  // layer 1 + layer 2 (MFMA GEMMs, bias added in gather, relu folded in gemm2)
  gemm_mfma<NFEAT, false><<<(NNODE + 63) / 64, 256, 0, stream>>>(feat, WT1hi, WT1lo, bufA, NNODE);
  gather_nodes<<<NNODE / 4, 256, 0, stream>>>(bufA, bufH, cursor, packed, b1);
  gemm_mfma<NHID, true><<<(NNODE + 63) / 64, 256, 0, stream>>>(bufH, WT2hi, WT2lo, bufA, NNODE);
  gather_nodes<<<NNODE / 4, 256, 0, stream>>>(bufA, bufH, cursor, packed, b2);

  // scoring
  int tot = NTPAD * NHID + NTEST * NHID + NTRAIN * NCLS + NTEST;
  gather_splits<<<(tot + 255) / 256, 256, 0, stream>>>(
      bufH, onehot, itr, ite, Thi, Tlo, Qhi, Qlo, lab, ccnt);
  score_mfma<<<dim3((NTEST + RB - 1) / RB, NCT), 512, 0, stream>>>(
      Qhi, Qlo, Thi, Tlo, ccnt, candv, candi);
  merge_topk<<<NTEST / 4, 256, 0, stream>>>(candv, candi, ccnt, lab, out);
}

// Round 8
// 448.400 us; speedup vs baseline: 1.7429x; 1.1142x over previous
//
#include <hip/hip_runtime.h>
#include <math.h>
#include <limits.h>

#define NNODE 50000
#define NEDGE 800000
#define NFEAT 256
#define NHID  128
#define NTEST 5000
#define NTRAIN 5000
#define NCLS  16
#define TOPK  20
#define CB    512           // cols per score block (32KB LDS -> 4 blocks/CU)
#define NCT   10            // col tiles (5120 padded)
#define RB    16            // rows per score block
#define NTPAD (NCT * CB)    // 5120
#define CCAP  640           // per-row candidate cap (10 tiles x <=64 fast / 20 dense)

typedef __attribute__((ext_vector_type(8))) short short8v;
typedef __attribute__((ext_vector_type(4))) short short4v;
typedef __attribute__((ext_vector_type(4))) float f32x4;

// swizzled score-LDS index (2-way max on writes and reads)
#define SWZ(r, c) ((r) * CB + (((c) + 4 * (r)) & (CB - 1)))

// ---------------- bf16 split helpers ----------------
__device__ inline void splitbf(float x, unsigned short& h, unsigned short& l) {
  unsigned u = __float_as_uint(x);
  unsigned hb = (u + 0x7fffu + ((u >> 16) & 1u)) >> 16;    // RNE to bf16
  float hf = __uint_as_float(hb << 16);
  float r = x - hf;
  unsigned ur = __float_as_uint(r);
  unsigned lb = (ur + 0x7fffu + ((ur >> 16) & 1u)) >> 16;
  h = (unsigned short)hb; l = (unsigned short)lb;
}

__device__ inline void split8(float4 a0, float4 a1, short8v& h, short8v& l) {
  unsigned short hh, ll;
  splitbf(a0.x, hh, ll); h[0] = (short)hh; l[0] = (short)ll;
  splitbf(a0.y, hh, ll); h[1] = (short)hh; l[1] = (short)ll;
  splitbf(a0.z, hh, ll); h[2] = (short)hh; l[2] = (short)ll;
  splitbf(a0.w, hh, ll); h[3] = (short)hh; l[3] = (short)ll;
  splitbf(a1.x, hh, ll); h[4] = (short)hh; l[4] = (short)ll;
  splitbf(a1.y, hh, ll); h[5] = (short)hh; l[5] = (short)ll;
  splitbf(a1.z, hh, ll); h[6] = (short)hh; l[6] = (short)ll;
  splitbf(a1.w, hh, ll); h[7] = (short)hh; l[7] = (short)ll;
}

// split W[K][128] -> WThi/WTlo [128][K] (transposed so B-frags are contiguous)
__global__ __launch_bounds__(256)
void split_w(const float* __restrict__ W, int KT,
             unsigned short* __restrict__ hi, unsigned short* __restrict__ lo) {
  int gid = blockIdx.x * 256 + threadIdx.x;
  if (gid < KT * 128) {
    int n = gid / KT, k = gid - n * KT;
    unsigned short h, l;
    splitbf(W[(size_t)k * 128 + n], h, l);
    hi[gid] = h; lo[gid] = l;
  }
}

// ---------------- MFMA GEMM: C[M x 128] = op(A)[M x KT] @ W ----------------
template<int KT, bool RELU>
__global__ __launch_bounds__(256)
void gemm_mfma(const float* __restrict__ A, const unsigned short* __restrict__ WThi,
               const unsigned short* __restrict__ WTlo, float* __restrict__ C, int M) {
  const int tid = threadIdx.x;
  const int w = tid >> 6, lane = tid & 63;
  const int m0 = blockIdx.x * 64 + w * 16;
  int arow = m0 + (lane & 15); if (arow > M - 1) arow = M - 1;
  const int koff = (lane >> 4) * 8;

  f32x4 acc[8];
#pragma unroll
  for (int t = 0; t < 8; ++t) acc[t] = {0.f, 0.f, 0.f, 0.f};

#pragma unroll
  for (int ks = 0; ks < KT / 32; ++ks) {
    const float* ap = &A[(size_t)arow * KT + ks * 32 + koff];
    float4 a0 = *reinterpret_cast<const float4*>(ap);
    float4 a1 = *reinterpret_cast<const float4*>(ap + 4);
    if (RELU) {
      a0.x=fmaxf(a0.x,0.f); a0.y=fmaxf(a0.y,0.f); a0.z=fmaxf(a0.z,0.f); a0.w=fmaxf(a0.w,0.f);
      a1.x=fmaxf(a1.x,0.f); a1.y=fmaxf(a1.y,0.f); a1.z=fmaxf(a1.z,0.f); a1.w=fmaxf(a1.w,0.f);
    }
    short8v ah, al;
    split8(a0, a1, ah, al);
#pragma unroll
    for (int t = 0; t < 8; ++t) {
      size_t bo = (size_t)(t * 16 + (lane & 15)) * KT + ks * 32 + koff;
      short8v bh = *reinterpret_cast<const short8v*>(&WThi[bo]);
      short8v bl = *reinterpret_cast<const short8v*>(&WTlo[bo]);
      acc[t] = __builtin_amdgcn_mfma_f32_16x16x32_bf16(ah, bh, acc[t], 0, 0, 0);
      acc[t] = __builtin_amdgcn_mfma_f32_16x16x32_bf16(ah, bl, acc[t], 0, 0, 0);
      acc[t] = __builtin_amdgcn_mfma_f32_16x16x32_bf16(al, bh, acc[t], 0, 0, 0);
    }
  }
  const int crow0 = m0 + (lane >> 4) * 4;
#pragma unroll
  for (int j = 0; j < 4; ++j) {
    int row = crow0 + j;
    if (row < M) {
#pragma unroll
      for (int t = 0; t < 8; ++t)
        C[(size_t)row * 128 + t * 16 + (lane & 15)] = acc[t][j];
    }
  }
}

// ---------------- CSR build ----------------
__global__ __launch_bounds__(256)
void zero_cnt(int* __restrict__ cnt) {
  int i = blockIdx.x * 256 + threadIdx.x;
  if (i < NNODE) cnt[i] = 0;
}

__global__ __launch_bounds__(256)
void hist_dst(const int* __restrict__ edst, int* __restrict__ cnt) {
  int e = blockIdx.x * 256 + threadIdx.x;
  if (e < NEDGE) atomicAdd(&cnt[edst[e]], 1);
}

#define SCHUNK 196
__global__ __launch_bounds__(256)
void scan_cnt(int* __restrict__ cnt) {
  __shared__ int part[256];
  const int t = threadIdx.x;
  const int base = t * SCHUNK;
  int s = 0;
  for (int i = 0; i < SCHUNK / 4; ++i) {
    int idx = base + i * 4;
    if (idx + 3 < NNODE) {
      int4 v = *reinterpret_cast<const int4*>(&cnt[idx]);
      s += v.x + v.y + v.z + v.w;
    } else {
      for (int j = 0; j < 4; ++j) if (idx + j < NNODE) s += cnt[idx + j];
    }
  }
  part[t] = s;
  __syncthreads();
  for (int off = 1; off < 256; off <<= 1) {
    int v = (t >= off) ? part[t - off] : 0;
    __syncthreads();
    part[t] += v;
    __syncthreads();
  }
  int run = part[t] - s;
  for (int i = 0; i < SCHUNK / 4; ++i) {
    int idx = base + i * 4;
    if (idx + 3 < NNODE) {
      int4 v = *reinterpret_cast<const int4*>(&cnt[idx]);
      int4 o;
      o.x = run; run += v.x; o.y = run; run += v.y;
      o.z = run; run += v.z; o.w = run; run += v.w;
      *reinterpret_cast<int4*>(&cnt[idx]) = o;
    } else {
      for (int j = 0; j < 4; ++j)
        if (idx + j < NNODE) { int c = cnt[idx + j]; cnt[idx + j] = run; run += c; }
    }
  }
}

__global__ __launch_bounds__(256)
void fill_csr(const int* __restrict__ esrc, const int* __restrict__ edst,
              const float* __restrict__ ew, int* __restrict__ cursor,
              int2* __restrict__ packed) {
  int e = blockIdx.x * 256 + threadIdx.x;
  if (e < NEDGE) {
    int d = edst[e];
    int p = atomicAdd(&cursor[d], 1);
    packed[p] = make_int2(esrc[e], __float_as_int(ew[e]));
  }
}

// ---------------- propagate (full, fp32 out): 1 wave/node, float4/lane ------
// Lane halves process even/odd edges (2 rows in flight) x2 unroll = 4 rows
// in flight per wave; cross-half reduce via shfl_xor(32).
__global__ __launch_bounds__(256)
void gather_nodes(const float* __restrict__ X, float* __restrict__ out,
                  const int* __restrict__ endoff, const int2* __restrict__ packed,
                  const float* __restrict__ bias) {
  const int tid = threadIdx.x;
  const int node = blockIdx.x * 4 + (tid >> 6);
  const int lane = tid & 63;
  const int half = lane >> 5, c4 = lane & 31;
  const int beg = node ? endoff[node - 1] : 0;
  const int end = endoff[node];
  const float4* X4 = reinterpret_cast<const float4*>(X);
  float4 a0 = {0.f, 0.f, 0.f, 0.f}, a1 = {0.f, 0.f, 0.f, 0.f};
  int e = beg + half;
  for (; e + 2 < end; e += 4) {
    int2 p0 = packed[e], p1 = packed[e + 2];
    float4 x0 = X4[(size_t)p0.x * 32 + c4];
    float4 x1 = X4[(size_t)p1.x * 32 + c4];
    float w0 = __int_as_float(p0.y), w1 = __int_as_float(p1.y);
    a0.x += w0 * x0.x; a0.y += w0 * x0.y; a0.z += w0 * x0.z; a0.w += w0 * x0.w;
    a1.x += w1 * x1.x; a1.y += w1 * x1.y; a1.z += w1 * x1.z; a1.w += w1 * x1.w;
  }
  for (; e < end; e += 2) {
    int2 p = packed[e];
    float4 x = X4[(size_t)p.x * 32 + c4];
    float w = __int_as_float(p.y);
    a0.x += w * x.x; a0.y += w * x.y; a0.z += w * x.z; a0.w += w * x.w;
  }
  a0.x += a1.x; a0.y += a1.y; a0.z += a1.z; a0.w += a1.w;
  a0.x += __shfl_xor(a0.x, 32); a0.y += __shfl_xor(a0.y, 32);
  a0.z += __shfl_xor(a0.z, 32); a0.w += __shfl_xor(a0.w, 32);
  if (half == 0) {
    float4 b = reinterpret_cast<const float4*>(bias)[c4];
    a0.x += b.x; a0.y += b.y; a0.z += b.z; a0.w += b.w;
    reinterpret_cast<float4*>(out)[(size_t)node * 32 + c4] = a0;
  }
}

// ---------------- targeted propagate + bias + bf16-split -------------------
// Computes emb rows ONLY for the 10120 scoring targets (5x less edge traffic
// than full propagate) and writes bf16 hi/lo directly (replaces gather_splits).
// tgt < NTPAD: train slot j (j<NTRAIN: node=itr[j], else zero pad row).
// tgt >= NTPAD: test slot j = tgt-NTPAD, node=ite[j].
__global__ __launch_bounds__(256)
void gather_targets(const float* __restrict__ X, const int* __restrict__ endoff,
                    const int2* __restrict__ packed, const float* __restrict__ b2,
                    const int* __restrict__ itr, const int* __restrict__ ite,
                    unsigned short* __restrict__ Thi, unsigned short* __restrict__ Tlo,
                    unsigned short* __restrict__ Qhi, unsigned short* __restrict__ Qlo) {
  const int tid = threadIdx.x;
  const int tgt = blockIdx.x * 4 + (tid >> 6);
  const int lane = tid & 63;
  const int half = lane >> 5, c4 = lane & 31;
  const bool isQ = tgt >= NTPAD;
  const int j = isQ ? tgt - NTPAD : tgt;
  int node = -1;
  if (isQ) { if (j < NTEST) node = ite[j]; }
  else if (j < NTRAIN) node = itr[j];

  float4 a0 = {0.f, 0.f, 0.f, 0.f};
  if (node >= 0) {                       // wave-uniform branch
    const int beg = node ? endoff[node - 1] : 0;
    const int end = endoff[node];
    const float4* X4 = reinterpret_cast<const float4*>(X);
    float4 a1 = {0.f, 0.f, 0.f, 0.f};
    int e = beg + half;
    for (; e + 2 < end; e += 4) {
      int2 p0 = packed[e], p1 = packed[e + 2];
      float4 x0 = X4[(size_t)p0.x * 32 + c4];
      float4 x1 = X4[(size_t)p1.x * 32 + c4];
      float w0 = __int_as_float(p0.y), w1 = __int_as_float(p1.y);
      a0.x += w0 * x0.x; a0.y += w0 * x0.y; a0.z += w0 * x0.z; a0.w += w0 * x0.w;
      a1.x += w1 * x1.x; a1.y += w1 * x1.y; a1.z += w1 * x1.z; a1.w += w1 * x1.w;
    }
    for (; e < end; e += 2) {
      int2 p = packed[e];
      float4 x = X4[(size_t)p.x * 32 + c4];
      float w = __int_as_float(p.y);
      a0.x += w * x.x; a0.y += w * x.y; a0.z += w * x.z; a0.w += w * x.w;
    }
    a0.x += a1.x; a0.y += a1.y; a0.z += a1.z; a0.w += a1.w;
    a0.x += __shfl_xor(a0.x, 32); a0.y += __shfl_xor(a0.y, 32);
    a0.z += __shfl_xor(a0.z, 32); a0.w += __shfl_xor(a0.w, 32);
    float4 b = reinterpret_cast<const float4*>(b2)[c4];
    a0.x += b.x; a0.y += b.y; a0.z += b.z; a0.w += b.w;
  }
  if (half == 0 && (isQ ? j < NTEST : j < NTPAD)) {
    unsigned short h, l;
    short4v hv, lv;
    splitbf(a0.x, h, l); hv[0] = (short)h; lv[0] = (short)l;
    splitbf(a0.y, h, l); hv[1] = (short)h; lv[1] = (short)l;
    splitbf(a0.z, h, l); hv[2] = (short)h; lv[2] = (short)l;
    splitbf(a0.w, h, l); hv[3] = (short)h; lv[3] = (short)l;
    size_t o = (size_t)j * 128 + c4 * 4;
    if (isQ) {
      *reinterpret_cast<short4v*>(&Qhi[o]) = hv;
      *reinterpret_cast<short4v*>(&Qlo[o]) = lv;
    } else {
      *reinterpret_cast<short4v*>(&Thi[o]) = hv;
      *reinterpret_cast<short4v*>(&Tlo[o]) = lv;
    }
  }
}

// ---------------- lab gather + ccnt zero ----------------
__global__ __launch_bounds__(256)
void prep_lab(const float* __restrict__ onehot, const int* __restrict__ itr,
              float* __restrict__ lab, int* __restrict__ ccnt) {
  int gid = blockIdx.x * 256 + threadIdx.x;
  if (gid < NTRAIN * NCLS) {
    int j = gid >> 4, c = gid & 15;
    lab[gid] = onehot[(size_t)itr[j] * NCLS + c];
  } else if (gid < NTRAIN * NCLS + NTEST) {
    ccnt[gid - NTRAIN * NCLS] = 0;
  }
}

// ---------------- MFMA score tile + threshold-filtered candidate append ------
__global__ __launch_bounds__(512)
void score_mfma(const unsigned short* __restrict__ Qhi, const unsigned short* __restrict__ Qlo,
                const unsigned short* __restrict__ Thi, const unsigned short* __restrict__ Tlo,
                int* __restrict__ ccnt, float* __restrict__ candv, int* __restrict__ candi) {
  __shared__ float s[RB * CB];         // 32 KB
  const int tid = threadIdx.x;
  const int w = tid >> 6, lane = tid & 63;   // w in 0..7
  const int r0 = blockIdx.x * RB;
  const int j0 = blockIdx.y * CB;

  int arow = r0 + (lane & 15); if (arow > NTEST - 1) arow = NTEST - 1;
  const int koff = (lane >> 4) * 8;
  short8v ah[4], al[4];
#pragma unroll
  for (int ks = 0; ks < 4; ++ks) {
    ah[ks] = *reinterpret_cast<const short8v*>(&Qhi[(size_t)arow * 128 + ks * 32 + koff]);
    al[ks] = *reinterpret_cast<const short8v*>(&Qlo[(size_t)arow * 128 + ks * 32 + koff]);
  }

#pragma unroll 2
  for (int t = 0; t < 4; ++t) {
    int colbase = w * 64 + t * 16;
    int col = j0 + colbase + (lane & 15);            // < NTPAD always
    const unsigned short* bh = &Thi[(size_t)col * 128 + koff];
    const unsigned short* bl = &Tlo[(size_t)col * 128 + koff];
    f32x4 a = {0.f, 0.f, 0.f, 0.f};
#pragma unroll
    for (int ks = 0; ks < 4; ++ks) {
      short8v bhv = *reinterpret_cast<const short8v*>(&bh[ks * 32]);
      short8v blv = *reinterpret_cast<const short8v*>(&bl[ks * 32]);
      a = __builtin_amdgcn_mfma_f32_16x16x32_bf16(ah[ks], bhv, a, 0, 0, 0);
      a = __builtin_amdgcn_mfma_f32_16x16x32_bf16(ah[ks], blv, a, 0, 0, 0);
      a = __builtin_amdgcn_mfma_f32_16x16x32_bf16(al[ks], bhv, a, 0, 0, 0);
    }
    int sc = colbase + (lane & 15);
    int sr = (lane >> 4) * 4;
#pragma unroll
    for (int r = 0; r < 4; ++r) s[SWZ(sr + r, sc)] = a[r];
  }
  __syncthreads();

  const unsigned long long ltm = ((unsigned long long)1 << lane) - 1;

#pragma unroll
  for (int r = 0; r < 2; ++r) {
    const int m = w * 2 + r;
    const int row = r0 + m;
    if (row >= NTEST) continue;
    float v[8];
#pragma unroll
    for (int k = 0; k < 8; ++k) {
      int c = lane + 64 * k;
      v[k] = (j0 + c < NTRAIN) ? s[SWZ(m, c)] : -INFINITY;
    }
    float t0 = fmaxf(v[0], v[1]), t1 = fmaxf(v[2], v[3]);
    float t2 = fmaxf(v[4], v[5]), t3 = fmaxf(v[6], v[7]);
    float sv = fmaxf(fmaxf(t0, t1), fmaxf(t2, t3));
    // bitonic sort (desc) of 64 lane-maxes, values only
#pragma unroll
    for (int k = 2; k <= 64; k <<= 1) {
#pragma unroll
      for (int j = k >> 1; j > 0; j >>= 1) {
        float ov = __shfl_xor(sv, j);
        bool keepMax = ((lane & j) == 0) == ((lane & k) == 0 || k == 64);
        sv = keepMax ? fmaxf(sv, ov) : fminf(sv, ov);
      }
    }
    float T = __shfl(sv, 19);       // 20th-largest lane-max

    int myo[8];
    int tot = 0;
#pragma unroll
    for (int k = 0; k < 8; ++k) {
      unsigned long long mk = __ballot(v[k] >= T);
      myo[k] = tot + (int)__popcll(mk & ltm);
      tot += (int)__popcll(mk);
    }
    if (tot <= 64) {                // typical tot ~ 22 (cap keeps CCAP=640 tight)
      int base = 0;
      if (lane == 0) base = atomicAdd(&ccnt[row], tot);
      base = __shfl(base, 0);
      float* cv = candv + (size_t)row * CCAP + base;
      int*   ci = candi + (size_t)row * CCAP + base;
#pragma unroll
      for (int k = 0; k < 8; ++k) {
        if (v[k] >= T) { cv[myo[k]] = v[k]; ci[myo[k]] = j0 + lane + 64 * k; }
      }
    } else {                        // rare dense path: exact top-20
      float selv = 0.f; int seli = 0;
#pragma unroll
      for (int it = 0; it < TOPK; ++it) {
        float bv = v[0]; int bk = 0;
#pragma unroll
        for (int k = 1; k < 8; ++k)
          if (v[k] > bv) { bv = v[k]; bk = k; }
        int bj = lane + 64 * bk;
#pragma unroll
        for (int off = 1; off < 64; off <<= 1) {
          float ov = __shfl_xor(bv, off);
          int   oj = __shfl_xor(bj, off);
          if (ov > bv || (ov == bv && oj < bj)) { bv = ov; bj = oj; }
        }
        if (lane == it) { selv = bv; seli = j0 + bj; }
        int ck = bj >> 6;
        if ((bj & 63) == lane) {
#pragma unroll
          for (int k = 0; k < 8; ++k)
            if (k == ck) v[k] = -INFINITY;
        }
      }
      int base = 0;
      if (lane == 0) base = atomicAdd(&ccnt[row], TOPK);
      base = __shfl(base, 0);
      if (lane < TOPK) {
        candv[(size_t)row * CCAP + base + lane] = selv;
        candi[(size_t)row * CCAP + base + lane] = seli;
      }
    }
  }
}

// 64-lane bitonic sort, descending by (value, then ascending index)
__device__ inline void sort64_vi(float& v, int& idx, int lane) {
#pragma unroll
  for (int k = 2; k <= 64; k <<= 1) {
#pragma unroll
    for (int j = k >> 1; j > 0; j >>= 1) {
      float ov = __shfl_xor(v, j);
      int   oi = __shfl_xor(idx, j);
      bool first = (v > ov) || (v == ov && idx < oi);
      bool keepMine = (((lane & j) == 0) == ((lane & k) == 0 || k == 64)) ? first : !first;
      if (!keepMine) { v = ov; idx = oi; }
    }
  }
}

// ---------------- merge: streaming bitonic top-20 + softmax + preds ----------
__global__ __launch_bounds__(256)
void merge_topk(const float* __restrict__ candv, const int* __restrict__ candi,
                const int* __restrict__ ccnt, const float* __restrict__ lab,
                float* __restrict__ out) {
  const int tid = threadIdx.x;
  const int wv = tid >> 6, lane = tid & 63;
  const int row = blockIdx.x * 4 + wv;
  const size_t base = (size_t)row * CCAP;
  const int C = ccnt[row];

  float v = -INFINITY; int idx = INT_MAX;
  int take = C < 64 ? C : 64;
  if (lane < take) { v = candv[base + lane]; idx = candi[base + lane]; }
  sort64_vi(v, idx, lane);
  int consumed = take;
  while (consumed < C) {
    int n = C - consumed; if (n > 44) n = 44;
    if (lane >= TOPK) {
      int p = lane - TOPK;
      if (p < n) { v = candv[base + consumed + p]; idx = candi[base + consumed + p]; }
      else       { v = -INFINITY; idx = INT_MAX; }
    }
    sort64_vi(v, idx, lane);
    consumed += n;
  }
  float mx = __shfl(v, 0);
  float wgt = (lane < TOPK) ? expf(v - mx) : 0.f;
  float sum = wgt;
#pragma unroll
  for (int off = 1; off < 64; off <<= 1) sum += __shfl_xor(sum, off);

  float acc = 0.f;
#pragma unroll
  for (int i = 0; i < TOPK; ++i) {
    float wi = __shfl(wgt, i);
    int   ji = __shfl(idx, i);
    if (lane < NCLS) acc += wi * lab[(size_t)ji * NCLS + lane];
  }
  if (lane < NCLS) out[(size_t)row * NCLS + lane] = acc / sum;
}

extern "C" void kernel_launch(void* const* d_in, const int* in_sizes, int n_in,
                              void* d_out, int out_size, void* d_ws, size_t ws_size,
                              hipStream_t stream) {
  const float* feat   = (const float*)d_in[0];
  const float* ew     = (const float*)d_in[1];
  const float* onehot = (const float*)d_in[2];
  const float* W1     = (const float*)d_in[3];
  const float* b1     = (const float*)d_in[4];
  const float* W2     = (const float*)d_in[5];
  const float* b2     = (const float*)d_in[6];
  const int*   ei     = (const int*)d_in[7];
  const int*   itr    = (const int*)d_in[8];
  const int*   ite    = (const int*)d_in[9];
  float* out = (float*)d_out;
  float* ws  = (float*)d_ws;

  float* bufA   = ws;                                  // [NNODE][128] X1/X2
  float* bufH   = bufA + (size_t)NNODE * NHID;         // [NNODE][128] h (dead after gemm2)
  int*   cursor = (int*)(bufH + (size_t)NNODE * NHID); // [NNODE]
  int2*  packed = (int2*)(cursor + ((NNODE + 15) & ~15)); // [NEDGE] (read by gather_targets!)
  unsigned short* WT1hi = (unsigned short*)(packed + NEDGE);    // [128][256]
  unsigned short* WT1lo = WT1hi + 128 * NFEAT;
  unsigned short* WT2hi = WT1lo + 128 * NFEAT;                  // [128][128]
  unsigned short* WT2lo = WT2hi + 128 * NHID;
  // T/Q/lab/ccnt live in bufH (dead after gemm2; gather_targets still reads packed)
  unsigned short* Thi = (unsigned short*)bufH;                  // [NTPAD][128]
  unsigned short* Tlo = Thi + (size_t)NTPAD * NHID;
  unsigned short* Qhi = Tlo + (size_t)NTPAD * NHID;             // [NTEST][128]
  unsigned short* Qlo = Qhi + (size_t)NTEST * NHID;
  float* lab  = (float*)(Qlo + (size_t)NTEST * NHID);           // [5000][16]
  int*   ccnt = (int*)(lab + (size_t)NTRAIN * NCLS);            // [5000]
  // candidates live in bufA (dead after gather_targets): 2 x 12.8 MB
  float* candv = bufA;                                          // [5000][640]
  int*   candi = (int*)(bufA + (size_t)NTEST * CCAP);

  const int* esrc = ei;
  const int* edst = ei + NEDGE;

  // CSR build + weight split
  zero_cnt<<<(NNODE + 255) / 256, 256, 0, stream>>>(cursor);
  hist_dst<<<(NEDGE + 255) / 256, 256, 0, stream>>>(edst, cursor);
  scan_cnt<<<1, 256, 0, stream>>>(cursor);
  fill_csr<<<(NEDGE + 255) / 256, 256, 0, stream>>>(esrc, edst, ew, cursor, packed);
  split_w<<<(NFEAT * 128 + 255) / 256, 256, 0, stream>>>(W1, NFEAT, WT1hi, WT1lo);
  split_w<<<(NHID * 128 + 255) / 256, 256, 0, stream>>>(W2, NHID, WT2hi, WT2lo);

  // layer 1 (full) ; layer 2 transform (full) ; layer-2 propagate (targets only)
  gemm_mfma<NFEAT, false><<<(NNODE + 63) / 64, 256, 0, stream>>>(feat, WT1hi, WT1lo, bufA, NNODE);
  gather_nodes<<<NNODE / 4, 256, 0, stream>>>(bufA, bufH, cursor, packed, b1);
  gemm_mfma<NHID, true><<<(NNODE + 63) / 64, 256, 0, stream>>>(bufH, WT2hi, WT2lo, bufA, NNODE);
  prep_lab<<<(NTRAIN * NCLS + NTEST + 255) / 256, 256, 0, stream>>>(onehot, itr, lab, ccnt);
  gather_targets<<<(NTPAD + NTEST) / 4, 256, 0, stream>>>(
      bufA, cursor, packed, b2, itr, ite, Thi, Tlo, Qhi, Qlo);

  // scoring
  score_mfma<<<dim3((NTEST + RB - 1) / RB, NCT), 512, 0, stream>>>(
      Qhi, Qlo, Thi, Tlo, ccnt, candv, candi);
  merge_topk<<<NTEST / 4, 256, 0, stream>>>(candv, candi, ccnt, lab, out);
}

// Round 9
// 429.515 us; speedup vs baseline: 1.8196x; 1.0440x over previous
//
#include <hip/hip_runtime.h>
#include <math.h>
#include <limits.h>

#define NNODE 50000
#define NEDGE 800000
#define NFEAT 256
#define NHID  128
#define NTEST 5000
#define NTRAIN 5000
#define NCLS  16
#define TOPK  20
#define CB    640           // cols per score block (40KB LDS -> 4 blocks/CU)
#define NCT   8             // col tiles == 8 XCDs (panel-per-XCD alignment)
#define RB    16            // rows per score block
#define NTPAD (NCT * CB)    // 5120
#define CCAP  512           // per-row candidate cap (8 tiles x <=64)

typedef __attribute__((ext_vector_type(8))) short short8v;
typedef __attribute__((ext_vector_type(4))) short short4v;
typedef __attribute__((ext_vector_type(4))) float f32x4;

// swizzled score-LDS index for stride-640 (640 % 32 == 0): shift cols by
// 8*(row>>2) so the 4 lane-quads of a ds_write hit disjoint 8-bank windows
// (2-way max = free); reads (c = lane + 64k) stay 2-way for any fixed row.
__device__ inline int swz(int r, int c) {
  int cc = c + 8 * (r >> 2);
  cc = (cc < CB) ? cc : cc - CB;
  return r * CB + cc;
}

// ---------------- bf16 split helpers ----------------
__device__ inline void splitbf(float x, unsigned short& h, unsigned short& l) {
  unsigned u = __float_as_uint(x);
  unsigned hb = (u + 0x7fffu + ((u >> 16) & 1u)) >> 16;    // RNE to bf16
  float hf = __uint_as_float(hb << 16);
  float r = x - hf;
  unsigned ur = __float_as_uint(r);
  unsigned lb = (ur + 0x7fffu + ((ur >> 16) & 1u)) >> 16;
  h = (unsigned short)hb; l = (unsigned short)lb;
}

__device__ inline void split8(float4 a0, float4 a1, short8v& h, short8v& l) {
  unsigned short hh, ll;
  splitbf(a0.x, hh, ll); h[0] = (short)hh; l[0] = (short)ll;
  splitbf(a0.y, hh, ll); h[1] = (short)hh; l[1] = (short)ll;
  splitbf(a0.z, hh, ll); h[2] = (short)hh; l[2] = (short)ll;
  splitbf(a0.w, hh, ll); h[3] = (short)hh; l[3] = (short)ll;
  splitbf(a1.x, hh, ll); h[4] = (short)hh; l[4] = (short)ll;
  splitbf(a1.y, hh, ll); h[5] = (short)hh; l[5] = (short)ll;
  splitbf(a1.z, hh, ll); h[6] = (short)hh; l[6] = (short)ll;
  splitbf(a1.w, hh, ll); h[7] = (short)hh; l[7] = (short)ll;
}

// ---------------- fused prep: zero cursor + split/transpose W1,W2 ----------
__global__ __launch_bounds__(256)
void prep0(int* __restrict__ cursor,
           const float* __restrict__ W1, unsigned short* __restrict__ WT1hi,
           unsigned short* __restrict__ WT1lo,
           const float* __restrict__ W2, unsigned short* __restrict__ WT2hi,
           unsigned short* __restrict__ WT2lo) {
  int gid = blockIdx.x * 256 + threadIdx.x;
  if (gid < NNODE) {
    cursor[gid] = 0;
  } else if (gid < NNODE + NFEAT * 128) {
    int i = gid - NNODE;
    int n = i / NFEAT, k = i - n * NFEAT;
    unsigned short h, l;
    splitbf(W1[(size_t)k * 128 + n], h, l);
    WT1hi[i] = h; WT1lo[i] = l;
  } else if (gid < NNODE + NFEAT * 128 + NHID * 128) {
    int i = gid - NNODE - NFEAT * 128;
    int n = i / NHID, k = i - n * NHID;
    unsigned short h, l;
    splitbf(W2[(size_t)k * 128 + n], h, l);
    WT2hi[i] = h; WT2lo[i] = l;
  }
}

// ---------------- MFMA GEMM: C[M x 128] = op(A)[M x KT] @ W ----------------
template<int KT, bool RELU>
__global__ __launch_bounds__(256)
void gemm_mfma(const float* __restrict__ A, const unsigned short* __restrict__ WThi,
               const unsigned short* __restrict__ WTlo, float* __restrict__ C, int M) {
  const int tid = threadIdx.x;
  const int w = tid >> 6, lane = tid & 63;
  const int m0 = blockIdx.x * 64 + w * 16;
  int arow = m0 + (lane & 15); if (arow > M - 1) arow = M - 1;
  const int koff = (lane >> 4) * 8;

  f32x4 acc[8];
#pragma unroll
  for (int t = 0; t < 8; ++t) acc[t] = {0.f, 0.f, 0.f, 0.f};

#pragma unroll
  for (int ks = 0; ks < KT / 32; ++ks) {
    const float* ap = &A[(size_t)arow * KT + ks * 32 + koff];
    float4 a0 = *reinterpret_cast<const float4*>(ap);
    float4 a1 = *reinterpret_cast<const float4*>(ap + 4);
    if (RELU) {
      a0.x=fmaxf(a0.x,0.f); a0.y=fmaxf(a0.y,0.f); a0.z=fmaxf(a0.z,0.f); a0.w=fmaxf(a0.w,0.f);
      a1.x=fmaxf(a1.x,0.f); a1.y=fmaxf(a1.y,0.f); a1.z=fmaxf(a1.z,0.f); a1.w=fmaxf(a1.w,0.f);
    }
    short8v ah, al;
    split8(a0, a1, ah, al);
#pragma unroll
    for (int t = 0; t < 8; ++t) {
      size_t bo = (size_t)(t * 16 + (lane & 15)) * KT + ks * 32 + koff;
      short8v bh = *reinterpret_cast<const short8v*>(&WThi[bo]);
      short8v bl = *reinterpret_cast<const short8v*>(&WTlo[bo]);
      acc[t] = __builtin_amdgcn_mfma_f32_16x16x32_bf16(ah, bh, acc[t], 0, 0, 0);
      acc[t] = __builtin_amdgcn_mfma_f32_16x16x32_bf16(ah, bl, acc[t], 0, 0, 0);
      acc[t] = __builtin_amdgcn_mfma_f32_16x16x32_bf16(al, bh, acc[t], 0, 0, 0);
    }
  }
  const int crow0 = m0 + (lane >> 4) * 4;
#pragma unroll
  for (int j = 0; j < 4; ++j) {
    int row = crow0 + j;
    if (row < M) {
#pragma unroll
      for (int t = 0; t < 8; ++t)
        C[(size_t)row * 128 + t * 16 + (lane & 15)] = acc[t][j];
    }
  }
}

// ---------------- CSR build ----------------
__global__ __launch_bounds__(256)
void hist_dst(const int* __restrict__ edst, int* __restrict__ cnt) {
  int e = blockIdx.x * 256 + threadIdx.x;
  if (e < NEDGE) atomicAdd(&cnt[edst[e]], 1);
}

#define SCHUNK 196
__global__ __launch_bounds__(256)
void scan_cnt(int* __restrict__ cnt) {
  __shared__ int part[256];
  const int t = threadIdx.x;
  const int base = t * SCHUNK;
  int s = 0;
  for (int i = 0; i < SCHUNK / 4; ++i) {
    int idx = base + i * 4;
    if (idx + 3 < NNODE) {
      int4 v = *reinterpret_cast<const int4*>(&cnt[idx]);
      s += v.x + v.y + v.z + v.w;
    } else {
      for (int j = 0; j < 4; ++j) if (idx + j < NNODE) s += cnt[idx + j];
    }
  }
  part[t] = s;
  __syncthreads();
  for (int off = 1; off < 256; off <<= 1) {
    int v = (t >= off) ? part[t - off] : 0;
    __syncthreads();
    part[t] += v;
    __syncthreads();
  }
  int run = part[t] - s;
  for (int i = 0; i < SCHUNK / 4; ++i) {
    int idx = base + i * 4;
    if (idx + 3 < NNODE) {
      int4 v = *reinterpret_cast<const int4*>(&cnt[idx]);
      int4 o;
      o.x = run; run += v.x; o.y = run; run += v.y;
      o.z = run; run += v.z; o.w = run; run += v.w;
      *reinterpret_cast<int4*>(&cnt[idx]) = o;
    } else {
      for (int j = 0; j < 4; ++j)
        if (idx + j < NNODE) { int c = cnt[idx + j]; cnt[idx + j] = run; run += c; }
    }
  }
}

__global__ __launch_bounds__(256)
void fill_csr(const int* __restrict__ esrc, const int* __restrict__ edst,
              const float* __restrict__ ew, int* __restrict__ cursor,
              int2* __restrict__ packed) {
  int e = blockIdx.x * 256 + threadIdx.x;
  if (e < NEDGE) {
    int d = edst[e];
    int p = atomicAdd(&cursor[d], 1);
    packed[p] = make_int2(esrc[e], __float_as_int(ew[e]));
  }
}

// ---------------- propagate (full, fp32 out): 1 wave/node, float4/lane ------
// Lane halves process even/odd edges; 4-deep unroll per half = 8 edge-rows
// in flight per wave (MLP for L3-latency-bound X reads).
__global__ __launch_bounds__(256)
void gather_nodes(const float* __restrict__ X, float* __restrict__ out,
                  const int* __restrict__ endoff, const int2* __restrict__ packed,
                  const float* __restrict__ bias) {
  const int tid = threadIdx.x;
  const int node = blockIdx.x * 4 + (tid >> 6);
  const int lane = tid & 63;
  const int half = lane >> 5, c4 = lane & 31;
  const int beg = node ? endoff[node - 1] : 0;
  const int end = endoff[node];
  const float4* X4 = reinterpret_cast<const float4*>(X);
  float4 a0 = {0.f,0.f,0.f,0.f}, a1 = {0.f,0.f,0.f,0.f};
  float4 a2 = {0.f,0.f,0.f,0.f}, a3 = {0.f,0.f,0.f,0.f};
  int e = beg + half;
  for (; e + 6 < end; e += 8) {
    int2 p0 = packed[e],     p1 = packed[e + 2];
    int2 p2 = packed[e + 4], p3 = packed[e + 6];
    float4 x0 = X4[(size_t)p0.x * 32 + c4];
    float4 x1 = X4[(size_t)p1.x * 32 + c4];
    float4 x2 = X4[(size_t)p2.x * 32 + c4];
    float4 x3 = X4[(size_t)p3.x * 32 + c4];
    float w0 = __int_as_float(p0.y), w1 = __int_as_float(p1.y);
    float w2 = __int_as_float(p2.y), w3 = __int_as_float(p3.y);
    a0.x += w0*x0.x; a0.y += w0*x0.y; a0.z += w0*x0.z; a0.w += w0*x0.w;
    a1.x += w1*x1.x; a1.y += w1*x1.y; a1.z += w1*x1.z; a1.w += w1*x1.w;
    a2.x += w2*x2.x; a2.y += w2*x2.y; a2.z += w2*x2.z; a2.w += w2*x2.w;
    a3.x += w3*x3.x; a3.y += w3*x3.y; a3.z += w3*x3.z; a3.w += w3*x3.w;
  }
  for (; e < end; e += 2) {
    int2 p = packed[e];
    float4 x = X4[(size_t)p.x * 32 + c4];
    float w = __int_as_float(p.y);
    a0.x += w*x.x; a0.y += w*x.y; a0.z += w*x.z; a0.w += w*x.w;
  }
  a0.x += a1.x + a2.x + a3.x; a0.y += a1.y + a2.y + a3.y;
  a0.z += a1.z + a2.z + a3.z; a0.w += a1.w + a2.w + a3.w;
  a0.x += __shfl_xor(a0.x, 32); a0.y += __shfl_xor(a0.y, 32);
  a0.z += __shfl_xor(a0.z, 32); a0.w += __shfl_xor(a0.w, 32);
  if (half == 0) {
    float4 b = reinterpret_cast<const float4*>(bias)[c4];
    a0.x += b.x; a0.y += b.y; a0.z += b.z; a0.w += b.w;
    reinterpret_cast<float4*>(out)[(size_t)node * 32 + c4] = a0;
  }
}

// ---------------- targeted propagate + bias + bf16-split -------------------
__global__ __launch_bounds__(256)
void gather_targets(const float* __restrict__ X, const int* __restrict__ endoff,
                    const int2* __restrict__ packed, const float* __restrict__ b2,
                    const int* __restrict__ itr, const int* __restrict__ ite,
                    unsigned short* __restrict__ Thi, unsigned short* __restrict__ Tlo,
                    unsigned short* __restrict__ Qhi, unsigned short* __restrict__ Qlo) {
  const int tid = threadIdx.x;
  const int tgt = blockIdx.x * 4 + (tid >> 6);
  const int lane = tid & 63;
  const int half = lane >> 5, c4 = lane & 31;
  const bool isQ = tgt >= NTPAD;
  const int j = isQ ? tgt - NTPAD : tgt;
  int node = -1;
  if (isQ) { if (j < NTEST) node = ite[j]; }
  else if (j < NTRAIN) node = itr[j];

  float4 a0 = {0.f, 0.f, 0.f, 0.f};
  if (node >= 0) {                       // wave-uniform branch
    const int beg = node ? endoff[node - 1] : 0;
    const int end = endoff[node];
    const float4* X4 = reinterpret_cast<const float4*>(X);
    float4 a1 = {0.f,0.f,0.f,0.f}, a2 = {0.f,0.f,0.f,0.f}, a3 = {0.f,0.f,0.f,0.f};
    int e = beg + half;
    for (; e + 6 < end; e += 8) {
      int2 p0 = packed[e],     p1 = packed[e + 2];
      int2 p2 = packed[e + 4], p3 = packed[e + 6];
      float4 x0 = X4[(size_t)p0.x * 32 + c4];
      float4 x1 = X4[(size_t)p1.x * 32 + c4];
      float4 x2 = X4[(size_t)p2.x * 32 + c4];
      float4 x3 = X4[(size_t)p3.x * 32 + c4];
      float w0 = __int_as_float(p0.y), w1 = __int_as_float(p1.y);
      float w2 = __int_as_float(p2.y), w3 = __int_as_float(p3.y);
      a0.x += w0*x0.x; a0.y += w0*x0.y; a0.z += w0*x0.z; a0.w += w0*x0.w;
      a1.x += w1*x1.x; a1.y += w1*x1.y; a1.z += w1*x1.z; a1.w += w1*x1.w;
      a2.x += w2*x2.x; a2.y += w2*x2.y; a2.z += w2*x2.z; a2.w += w2*x2.w;
      a3.x += w3*x3.x; a3.y += w3*x3.y; a3.z += w3*x3.z; a3.w += w3*x3.w;
    }
    for (; e < end; e += 2) {
      int2 p = packed[e];
      float4 x = X4[(size_t)p.x * 32 + c4];
      float w = __int_as_float(p.y);
      a0.x += w*x.x; a0.y += w*x.y; a0.z += w*x.z; a0.w += w*x.w;
    }
    a0.x += a1.x + a2.x + a3.x; a0.y += a1.y + a2.y + a3.y;
    a0.z += a1.z + a2.z + a3.z; a0.w += a1.w + a2.w + a3.w;
    a0.x += __shfl_xor(a0.x, 32); a0.y += __shfl_xor(a0.y, 32);
    a0.z += __shfl_xor(a0.z, 32); a0.w += __shfl_xor(a0.w, 32);
    float4 b = reinterpret_cast<const float4*>(b2)[c4];
    a0.x += b.x; a0.y += b.y; a0.z += b.z; a0.w += b.w;
  }
  if (half == 0 && (isQ ? j < NTEST : j < NTPAD)) {
    unsigned short h, l;
    short4v hv, lv;
    splitbf(a0.x, h, l); hv[0] = (short)h; lv[0] = (short)l;
    splitbf(a0.y, h, l); hv[1] = (short)h; lv[1] = (short)l;
    splitbf(a0.z, h, l); hv[2] = (short)h; lv[2] = (short)l;
    splitbf(a0.w, h, l); hv[3] = (short)h; lv[3] = (short)l;
    size_t o = (size_t)j * 128 + c4 * 4;
    if (isQ) {
      *reinterpret_cast<short4v*>(&Qhi[o]) = hv;
      *reinterpret_cast<short4v*>(&Qlo[o]) = lv;
    } else {
      *reinterpret_cast<short4v*>(&Thi[o]) = hv;
      *reinterpret_cast<short4v*>(&Tlo[o]) = lv;
    }
  }
}

// ---------------- lab gather + ccnt zero ----------------
__global__ __launch_bounds__(256)
void prep_lab(const float* __restrict__ onehot, const int* __restrict__ itr,
              float* __restrict__ lab, int* __restrict__ ccnt) {
  int gid = blockIdx.x * 256 + threadIdx.x;
  if (gid < NTRAIN * NCLS) {
    int j = gid >> 4, c = gid & 15;
    lab[gid] = onehot[(size_t)itr[j] * NCLS + c];
  } else if (gid < NTRAIN * NCLS + NTEST) {
    ccnt[gid - NTRAIN * NCLS] = 0;
  }
}

// ---------------- MFMA score tile + threshold-filtered candidate append ------
// 1D grid 313*8: y = bid&7 (T panel) aligns with XCD = bid%8 so each XCD's
// private L2 holds exactly one 327KB T-panel for all its 313 row-blocks
// (kills the 8x HBM panel re-fetch seen in r8: FETCH 22.8MB for a 2.9MB set).
// 512 thr = 8 waves; wave w: cols [80w, 80w+80) = 5 tiles x 12 MFMA.
__global__ __launch_bounds__(512)
void score_mfma(const unsigned short* __restrict__ Qhi, const unsigned short* __restrict__ Qlo,
                const unsigned short* __restrict__ Thi, const unsigned short* __restrict__ Tlo,
                int* __restrict__ ccnt, float* __restrict__ candv, int* __restrict__ candi) {
  __shared__ float s[RB * CB];         // 40 KB
  const int tid = threadIdx.x;
  const int w = tid >> 6, lane = tid & 63;   // w in 0..7
  const int r0 = (blockIdx.x >> 3) * RB;
  const int j0 = (blockIdx.x & 7) * CB;

  int arow = r0 + (lane & 15); if (arow > NTEST - 1) arow = NTEST - 1;
  const int koff = (lane >> 4) * 8;
  short8v ah[4], al[4];
#pragma unroll
  for (int ks = 0; ks < 4; ++ks) {
    ah[ks] = *reinterpret_cast<const short8v*>(&Qhi[(size_t)arow * 128 + ks * 32 + koff]);
    al[ks] = *reinterpret_cast<const short8v*>(&Qlo[(size_t)arow * 128 + ks * 32 + koff]);
  }

#pragma unroll
  for (int t = 0; t < 5; ++t) {
    int colbase = w * 80 + t * 16;
    int col = j0 + colbase + (lane & 15);            // < NTPAD always
    const unsigned short* bh = &Thi[(size_t)col * 128 + koff];
    const unsigned short* bl = &Tlo[(size_t)col * 128 + koff];
    f32x4 a = {0.f, 0.f, 0.f, 0.f};
#pragma unroll
    for (int ks = 0; ks < 4; ++ks) {
      short8v bhv = *reinterpret_cast<const short8v*>(&bh[ks * 32]);
      short8v blv = *reinterpret_cast<const short8v*>(&bl[ks * 32]);
      a = __builtin_amdgcn_mfma_f32_16x16x32_bf16(ah[ks], bhv, a, 0, 0, 0);
      a = __builtin_amdgcn_mfma_f32_16x16x32_bf16(ah[ks], blv, a, 0, 0, 0);
      a = __builtin_amdgcn_mfma_f32_16x16x32_bf16(al[ks], bhv, a, 0, 0, 0);
    }
    int sc = colbase + (lane & 15);
    int sr = (lane >> 4) * 4;
#pragma unroll
    for (int r = 0; r < 4; ++r) s[swz(sr + r, sc)] = a[r];
  }
  __syncthreads();

  const unsigned long long ltm = ((unsigned long long)1 << lane) - 1;

#pragma unroll
  for (int r = 0; r < 2; ++r) {
    const int m = w * 2 + r;
    const int row = r0 + m;
    if (row >= NTEST) continue;
    float v[10];
#pragma unroll
    for (int k = 0; k < 10; ++k) {
      int c = lane + 64 * k;
      v[k] = (j0 + c < NTRAIN) ? s[swz(m, c)] : -INFINITY;
    }
    float t0 = fmaxf(v[0], v[1]), t1 = fmaxf(v[2], v[3]);
    float t2 = fmaxf(v[4], v[5]), t3 = fmaxf(v[6], v[7]);
    float sv = fmaxf(fmaxf(fmaxf(t0, t1), fmaxf(t2, t3)), fmaxf(v[8], v[9]));
    // bitonic sort (desc) of 64 lane-maxes, values only
#pragma unroll
    for (int k = 2; k <= 64; k <<= 1) {
#pragma unroll
      for (int j = k >> 1; j > 0; j >>= 1) {
        float ov = __shfl_xor(sv, j);
        bool keepMax = ((lane & j) == 0) == ((lane & k) == 0 || k == 64);
        sv = keepMax ? fmaxf(sv, ov) : fminf(sv, ov);
      }
    }
    float T = __shfl(sv, 19);       // 20th-largest lane-max

    int myo[10];
    int tot = 0;
#pragma unroll
    for (int k = 0; k < 10; ++k) {
      unsigned long long mk = __ballot(v[k] >= T);
      myo[k] = tot + (int)__popcll(mk & ltm);
      tot += (int)__popcll(mk);
    }
    if (tot <= 64) {                // typical tot ~ 22
      int base = 0;
      if (lane == 0) base = atomicAdd(&ccnt[row], tot);
      base = __shfl(base, 0);
      float* cv = candv + (size_t)row * CCAP + base;
      int*   ci = candi + (size_t)row * CCAP + base;
#pragma unroll
      for (int k = 0; k < 10; ++k) {
        if (v[k] >= T) { cv[myo[k]] = v[k]; ci[myo[k]] = j0 + lane + 64 * k; }
      }
    } else {                        // rare dense path: exact top-20
      float selv = 0.f; int seli = 0;
#pragma unroll
      for (int it = 0; it < TOPK; ++it) {
        float bv = v[0]; int bk = 0;
#pragma unroll
        for (int k = 1; k < 10; ++k)
          if (v[k] > bv) { bv = v[k]; bk = k; }
        int bj = lane + 64 * bk;
#pragma unroll
        for (int off = 1; off < 64; off <<= 1) {
          float ov = __shfl_xor(bv, off);
          int   oj = __shfl_xor(bj, off);
          if (ov > bv || (ov == bv && oj < bj)) { bv = ov; bj = oj; }
        }
        if (lane == it) { selv = bv; seli = j0 + bj; }
        int ck = bj >> 6;
        if ((bj & 63) == lane) {
#pragma unroll
          for (int k = 0; k < 10; ++k)
            if (k == ck) v[k] = -INFINITY;
        }
      }
      int base = 0;
      if (lane == 0) base = atomicAdd(&ccnt[row], TOPK);
      base = __shfl(base, 0);
      if (lane < TOPK) {
        candv[(size_t)row * CCAP + base + lane] = selv;
        candi[(size_t)row * CCAP + base + lane] = seli;
      }
    }
  }
}

// 64-lane bitonic sort, descending by (value, then ascending index)
__device__ inline void sort64_vi(float& v, int& idx, int lane) {
#pragma unroll
  for (int k = 2; k <= 64; k <<= 1) {
#pragma unroll
    for (int j = k >> 1; j > 0; j >>= 1) {
      float ov = __shfl_xor(v, j);
      int   oi = __shfl_xor(idx, j);
      bool first = (v > ov) || (v == ov && idx < oi);
      bool keepMine = (((lane & j) == 0) == ((lane & k) == 0 || k == 64)) ? first : !first;
      if (!keepMine) { v = ov; idx = oi; }
    }
  }
}

// ---------------- merge: streaming bitonic top-20 + softmax + preds ----------
__global__ __launch_bounds__(256)
void merge_topk(const float* __restrict__ candv, const int* __restrict__ candi,
                const int* __restrict__ ccnt, const float* __restrict__ lab,
                float* __restrict__ out) {
  const int tid = threadIdx.x;
  const int wv = tid >> 6, lane = tid & 63;
  const int row = blockIdx.x * 4 + wv;
  const size_t base = (size_t)row * CCAP;
  const int C = ccnt[row];

  float v = -INFINITY; int idx = INT_MAX;
  int take = C < 64 ? C : 64;
  if (lane < take) { v = candv[base + lane]; idx = candi[base + lane]; }
  sort64_vi(v, idx, lane);
  int consumed = take;
  while (consumed < C) {
    int n = C - consumed; if (n > 44) n = 44;
    if (lane >= TOPK) {
      int p = lane - TOPK;
      if (p < n) { v = candv[base + consumed + p]; idx = candi[base + consumed + p]; }
      else       { v = -INFINITY; idx = INT_MAX; }
    }
    sort64_vi(v, idx, lane);
    consumed += n;
  }
  float mx = __shfl(v, 0);
  float wgt = (lane < TOPK) ? expf(v - mx) : 0.f;
  float sum = wgt;
#pragma unroll
  for (int off = 1; off < 64; off <<= 1) sum += __shfl_xor(sum, off);

  float acc = 0.f;
#pragma unroll
  for (int i = 0; i < TOPK; ++i) {
    float wi = __shfl(wgt, i);
    int   ji = __shfl(idx, i);
    if (lane < NCLS) acc += wi * lab[(size_t)ji * NCLS + lane];
  }
  if (lane < NCLS) out[(size_t)row * NCLS + lane] = acc / sum;
}

extern "C" void kernel_launch(void* const* d_in, const int* in_sizes, int n_in,
                              void* d_out, int out_size, void* d_ws, size_t ws_size,
                              hipStream_t stream) {
  const float* feat   = (const float*)d_in[0];
  const float* ew     = (const float*)d_in[1];
  const float* onehot = (const float*)d_in[2];
  const float* W1     = (const float*)d_in[3];
  const float* b1     = (const float*)d_in[4];
  const float* W2     = (const float*)d_in[5];
  const float* b2     = (const float*)d_in[6];
  const int*   ei     = (const int*)d_in[7];
  const int*   itr    = (const int*)d_in[8];
  const int*   ite    = (const int*)d_in[9];
  float* out = (float*)d_out;
  float* ws  = (float*)d_ws;

  float* bufA   = ws;                                  // [NNODE][128] X1/X2
  float* bufH   = bufA + (size_t)NNODE * NHID;         // [NNODE][128] h (dead after gemm2)
  int*   cursor = (int*)(bufH + (size_t)NNODE * NHID); // [NNODE]
  int2*  packed = (int2*)(cursor + ((NNODE + 15) & ~15)); // [NEDGE] (read by gather_targets!)
  unsigned short* WT1hi = (unsigned short*)(packed + NEDGE);    // [128][256]
  unsigned short* WT1lo = WT1hi + 128 * NFEAT;
  unsigned short* WT2hi = WT1lo + 128 * NFEAT;                  // [128][128]
  unsigned short* WT2lo = WT2hi + 128 * NHID;
  // T/Q/lab/ccnt live in bufH (dead after gemm2; gather_targets still reads packed)
  unsigned short* Thi = (unsigned short*)bufH;                  // [NTPAD][128]
  unsigned short* Tlo = Thi + (size_t)NTPAD * NHID;
  unsigned short* Qhi = Tlo + (size_t)NTPAD * NHID;             // [NTEST][128]
  unsigned short* Qlo = Qhi + (size_t)NTEST * NHID;
  float* lab  = (float*)(Qlo + (size_t)NTEST * NHID);           // [5000][16]
  int*   ccnt = (int*)(lab + (size_t)NTRAIN * NCLS);            // [5000]
  // candidates live in bufA (dead after gather_targets): 2 x 10.2 MB
  float* candv = bufA;                                          // [5000][512]
  int*   candi = (int*)(bufA + (size_t)NTEST * CCAP);

  const int* esrc = ei;
  const int* edst = ei + NEDGE;

  // prep (cursor zero + weight split) + CSR build
  prep0<<<(NNODE + NFEAT * 128 + NHID * 128 + 255) / 256, 256, 0, stream>>>(
      cursor, W1, WT1hi, WT1lo, W2, WT2hi, WT2lo);
  hist_dst<<<(NEDGE + 255) / 256, 256, 0, stream>>>(edst, cursor);
  scan_cnt<<<1, 256, 0, stream>>>(cursor);
  fill_csr<<<(NEDGE + 255) / 256, 256, 0, stream>>>(esrc, edst, ew, cursor, packed);

  // layer 1 (full) ; layer 2 transform (full) ; layer-2 propagate (targets only)
  gemm_mfma<NFEAT, false><<<(NNODE + 63) / 64, 256, 0, stream>>>(feat, WT1hi, WT1lo, bufA, NNODE);
  gather_nodes<<<NNODE / 4, 256, 0, stream>>>(bufA, bufH, cursor, packed, b1);
  gemm_mfma<NHID, true><<<(NNODE + 63) / 64, 256, 0, stream>>>(bufH, WT2hi, WT2lo, bufA, NNODE);
  prep_lab<<<(NTRAIN * NCLS + NTEST + 255) / 256, 256, 0, stream>>>(onehot, itr, lab, ccnt);
  gather_targets<<<(NTPAD + NTEST) / 4, 256, 0, stream>>>(
      bufA, cursor, packed, b2, itr, ite, Thi, Tlo, Qhi, Qlo);

  // scoring (panel-per-XCD 1D grid)
  score_mfma<<<((NTEST + RB - 1) / RB) * NCT, 512, 0, stream>>>(
      Qhi, Qlo, Thi, Tlo, ccnt, candv, candi);
  merge_topk<<<NTEST / 4, 256, 0, stream>>>(candv, candi, ccnt, lab, out);
}